// Round 1
// baseline (5141.452 us; speedup 1.0000x reference)
//
#include <hip/hip_runtime.h>
#include <hip/hip_bf16.h>

#define H 128
#define RB 16
#define LATD 32

__device__ __forceinline__ float silu_f(float x) {
  return x / (1.0f + __expf(-x));
}

// 4x4 register-blocked GEMM microkernel: rows from LDS (ldx stride), weights
// from global W (row-major KxH, ld=H), columns c0..c0+3.
template<int K>
__device__ __forceinline__ void mm4x4(const float* X0, int ldx,
                                      const float* __restrict__ W, int c0,
                                      float acc[4][4]) {
  #pragma unroll 4
  for (int k = 0; k < K; k += 4) {
    float4 xv[4], w4[4];
    #pragma unroll
    for (int rr = 0; rr < 4; ++rr) xv[rr] = *(const float4*)(X0 + rr * ldx + k);
    #pragma unroll
    for (int kk = 0; kk < 4; ++kk) w4[kk] = *(const float4*)(W + (size_t)(k + kk) * H + c0);
    const float* x = (const float*)xv;
    const float* w = (const float*)w4;
    #pragma unroll
    for (int rr = 0; rr < 4; ++rr)
      #pragma unroll
      for (int cc = 0; cc < 4; ++cc)
        acc[rr][cc] += x[rr*4+0]*w[cc] + x[rr*4+1]*w[4+cc] +
                       x[rr*4+2]*w[8+cc] + x[rr*4+3]*w[12+cc];
  }
}

__global__ void k_init_h(const float* __restrict__ atom_embed,
                         const float* __restrict__ residue_embed,
                         const int* __restrict__ atype,
                         const int* __restrict__ ridx,
                         const int* __restrict__ rtype,
                         float* __restrict__ h, int A) {
  int i = blockIdx.x * blockDim.x + threadIdx.x;
  if (i >= A * H) return;
  int a = i >> 7, j = i & 127;
  int t = atype[a];
  int rt = rtype[ridx[a]];
  h[i] = atom_embed[t * H + j] + residue_embed[rt * H + j];
}

__global__ void k_dist(const float* __restrict__ coords,
                       const int* __restrict__ esrc, const int* __restrict__ edst,
                       float* __restrict__ dbuf, int E) {
  int e = blockIdx.x * blockDim.x + threadIdx.x;
  if (e >= E) return;
  int s = esrc[e], t = edst[e];
  float dx = coords[3*s+0] - coords[3*t+0];
  float dy = coords[3*s+1] - coords[3*t+1];
  float dz = coords[3*s+2] - coords[3*t+2];
  dbuf[e] = sqrtf(dx*dx + dy*dy + dz*dz);
}

__global__ void k_starts(const int* __restrict__ ridx, int* __restrict__ starts, int A) {
  int a = blockIdx.x * blockDim.x + threadIdx.x;
  if (a >= A) return;
  if (a == 0 || ridx[a] != ridx[a-1]) starts[ridx[a]] = a;
}

// Edge MLP + scatter-add into agg. 32 edges per block, 256 threads.
__global__ __launch_bounds__(256) void k_edge(
    const float* __restrict__ h, const float* __restrict__ dbuf,
    const int* __restrict__ esrc, const int* __restrict__ edst,
    const float* __restrict__ We1, const float* __restrict__ be1,
    const float* __restrict__ We2, const float* __restrict__ be2,
    float* __restrict__ agg, int E) {
  __shared__ float X[32][276];   // [h_src | h_dst | rbf], 272 used
  __shared__ float M1[32][132];  // 128 used
  const int tid = threadIdx.x, lane = tid & 63, wv = tid >> 6;
  const int e0 = blockIdx.x * 32;
  #pragma unroll
  for (int i = 0; i < 8; ++i) {
    int r = wv * 8 + i;
    int e = e0 + r; if (e >= E) e = E - 1;
    int s = esrc[e], t = edst[e];
    X[r][lane]        = h[(size_t)s*H + lane];
    X[r][64 + lane]   = h[(size_t)s*H + 64 + lane];
    X[r][128 + lane]  = h[(size_t)t*H + lane];
    X[r][192 + lane]  = h[(size_t)t*H + 64 + lane];
    if (lane < RB) {
      float d = dbuf[e];
      float c = (float)lane * (5.0f / 15.0f);
      float dd = d - c;
      X[r][256 + lane] = __expf(-10.24f * dd * dd);
    }
  }
  __syncthreads();
  const int rowg = tid >> 5, c0 = (tid & 31) * 4;
  float acc[4][4] = {};
  mm4x4<272>(&X[rowg*4][0], 276, We1, c0, acc);
  #pragma unroll
  for (int rr = 0; rr < 4; ++rr)
    #pragma unroll
    for (int cc = 0; cc < 4; ++cc)
      M1[rowg*4+rr][c0+cc] = silu_f(acc[rr][cc] + be1[c0+cc]);
  __syncthreads();
  float acc2[4][4] = {};
  mm4x4<128>(&M1[rowg*4][0], 132, We2, c0, acc2);
  #pragma unroll
  for (int rr = 0; rr < 4; ++rr) {
    int e = e0 + rowg*4 + rr;
    if (e < E) {
      int t = edst[e];
      #pragma unroll
      for (int cc = 0; cc < 4; ++cc)
        atomicAdd(&agg[(size_t)t*H + c0 + cc], silu_f(acc2[rr][cc] + be2[c0+cc]));
    }
  }
}

// Node MLP: u = silu([h|agg]@Wh1+bh1); h += u@Wh2+bh2. 32 atoms/block.
__global__ __launch_bounds__(256) void k_node(
    float* __restrict__ h, const float* __restrict__ agg,
    const float* __restrict__ Wh1, const float* __restrict__ bh1,
    const float* __restrict__ Wh2, const float* __restrict__ bh2, int A) {
  __shared__ float X[32][260];   // [h | agg], 256 used
  __shared__ float U[32][132];
  const int tid = threadIdx.x, lane = tid & 63, wv = tid >> 6;
  const int a0 = blockIdx.x * 32;
  #pragma unroll
  for (int i = 0; i < 8; ++i) {
    int r = wv * 8 + i;
    int a = a0 + r; if (a >= A) a = A - 1;
    X[r][lane]       = h[(size_t)a*H + lane];
    X[r][64 + lane]  = h[(size_t)a*H + 64 + lane];
    X[r][128 + lane] = agg[(size_t)a*H + lane];
    X[r][192 + lane] = agg[(size_t)a*H + 64 + lane];
  }
  __syncthreads();
  const int rowg = tid >> 5, c0 = (tid & 31) * 4;
  float acc[4][4] = {};
  mm4x4<256>(&X[rowg*4][0], 260, Wh1, c0, acc);
  #pragma unroll
  for (int rr = 0; rr < 4; ++rr)
    #pragma unroll
    for (int cc = 0; cc < 4; ++cc)
      U[rowg*4+rr][c0+cc] = silu_f(acc[rr][cc] + bh1[c0+cc]);
  __syncthreads();
  float acc2[4][4] = {};
  mm4x4<128>(&U[rowg*4][0], 132, Wh2, c0, acc2);
  #pragma unroll
  for (int rr = 0; rr < 4; ++rr) {
    int a = a0 + rowg*4 + rr;
    if (a < A)
      #pragma unroll
      for (int cc = 0; cc < 4; ++cc)
        h[(size_t)a*H + c0 + cc] += acc2[rr][cc] + bh2[c0+cc];
  }
}

// out = in @ W + b  (in: nrows x H), 32 rows/block
__global__ __launch_bounds__(256) void k_linear(
    const float* __restrict__ in, const float* __restrict__ W,
    const float* __restrict__ b, float* __restrict__ out, int nrows) {
  __shared__ float X[32][132];
  const int tid = threadIdx.x, lane = tid & 63, wv = tid >> 6;
  const int r0 = blockIdx.x * 32;
  #pragma unroll
  for (int i = 0; i < 8; ++i) {
    int r = wv * 8 + i;
    int a = r0 + r; if (a >= nrows) a = nrows - 1;
    X[r][lane]      = in[(size_t)a*H + lane];
    X[r][64 + lane] = in[(size_t)a*H + 64 + lane];
  }
  __syncthreads();
  const int rowg = tid >> 5, c0 = (tid & 31) * 4;
  float acc[4][4] = {};
  mm4x4<128>(&X[rowg*4][0], 132, W, c0, acc);
  #pragma unroll
  for (int rr = 0; rr < 4; ++rr) {
    int a = r0 + rowg*4 + rr;
    if (a < nrows)
      #pragma unroll
      for (int cc = 0; cc < 4; ++cc)
        out[(size_t)a*H + c0 + cc] = acc[rr][cc] + b[c0+cc];
  }
}

// q = residue_embed[rtype] @ Wq + bq  (one thread per output)
__global__ void k_q(const float* __restrict__ residue_embed,
                    const int* __restrict__ rtype,
                    const float* __restrict__ Wq, const float* __restrict__ bq,
                    float* __restrict__ q, int N) {
  int i = blockIdx.x * blockDim.x + threadIdx.x;
  if (i >= N * H) return;
  int r = i >> 7, j = i & 127;
  const float* emb = residue_embed + (size_t)rtype[r] * H;
  float s = bq[j];
  #pragma unroll 4
  for (int k = 0; k < H; ++k) s += emb[k] * Wq[(size_t)k*H + j];
  q[i] = s;
}

// Per-residue attention pooling. One wave per residue; atoms contiguous.
__global__ __launch_bounds__(256) void k_pool(
    const float* __restrict__ q, const float* __restrict__ kbuf,
    const float* __restrict__ vbuf, const int* __restrict__ starts,
    const int* __restrict__ apr, float* __restrict__ pooled, int N) {
  int r = blockIdx.x * 4 + (threadIdx.x >> 6);
  if (r >= N) return;
  int lane = threadIdx.x & 63;
  int s0 = starts[r], cnt = apr[r];
  float q0 = q[(size_t)r*H + lane], q1 = q[(size_t)r*H + 64 + lane];
  float myscore = -1e30f;
  for (int i = 0; i < cnt; ++i) {
    size_t a = (size_t)(s0 + i) * H;
    float p = q0 * kbuf[a + lane] + q1 * kbuf[a + 64 + lane];
    #pragma unroll
    for (int off = 32; off; off >>= 1) p += __shfl_xor(p, off);
    if (lane == i) myscore = p * 0.08838834764831845f;  // 128^-0.5
  }
  float val = (lane < cnt) ? myscore : -1e30f;
  float mx = val;
  #pragma unroll
  for (int off = 32; off; off >>= 1) mx = fmaxf(mx, __shfl_xor(mx, off));
  float ex = (lane < cnt) ? __expf(val - mx) : 0.0f;
  float sum = ex;
  #pragma unroll
  for (int off = 32; off; off >>= 1) sum += __shfl_xor(sum, off);
  float w = ex / sum;
  float p0 = 0.f, p1 = 0.f;
  for (int i = 0; i < cnt; ++i) {
    float wi = __shfl(w, i);
    size_t a = (size_t)(s0 + i) * H;
    p0 += wi * vbuf[a + lane];
    p1 += wi * vbuf[a + 64 + lane];
  }
  pooled[(size_t)r*H + lane] = p0;
  pooled[(size_t)r*H + 64 + lane] = p1;
}

__global__ void k_head(const float* __restrict__ pooled,
                       const float* __restrict__ Wmu, const float* __restrict__ bmu,
                       const float* __restrict__ Wlv, const float* __restrict__ blv,
                       float* __restrict__ out, int N) {
  int i = blockIdx.x * blockDim.x + threadIdx.x;
  if (i >= N * LATD) return;
  int r = i >> 5, j = i & 31;
  const float* p = pooled + (size_t)r * H;
  float smu = 0.f, slv = 0.f;
  #pragma unroll 4
  for (int k = 0; k < H; ++k) {
    float pv = p[k];
    smu += pv * Wmu[(size_t)k*LATD + j];
    slv += pv * Wlv[(size_t)k*LATD + j];
  }
  smu += bmu[j];
  slv += blv[j];
  slv = fminf(fmaxf(slv, -10.0f), 2.0f);
  out[i] = smu;
  out[(size_t)N*LATD + i] = slv;
}

extern "C" void kernel_launch(void* const* d_in, const int* in_sizes, int n_in,
                              void* d_out, int out_size, void* d_ws, size_t ws_size,
                              hipStream_t stream) {
  const float* coords        = (const float*)d_in[0];
  const int*   atype         = (const int*)d_in[1];
  const int*   ridx          = (const int*)d_in[2];
  const int*   rtype         = (const int*)d_in[3];
  const int*   apr           = (const int*)d_in[4];
  const int*   esrc          = (const int*)d_in[5];
  const int*   edst          = (const int*)d_in[6];
  const float* atom_embed    = (const float*)d_in[7];
  const float* residue_embed = (const float*)d_in[8];
  const float* We1 = (const float*)d_in[9];
  const float* be1 = (const float*)d_in[10];
  const float* We2 = (const float*)d_in[11];
  const float* be2 = (const float*)d_in[12];
  const float* Wh1 = (const float*)d_in[13];
  const float* bh1 = (const float*)d_in[14];
  const float* Wh2 = (const float*)d_in[15];
  const float* bh2 = (const float*)d_in[16];
  const float* Wq  = (const float*)d_in[17];
  const float* bq  = (const float*)d_in[18];
  const float* Wk  = (const float*)d_in[19];
  const float* bk  = (const float*)d_in[20];
  const float* Wv  = (const float*)d_in[21];
  const float* bv  = (const float*)d_in[22];
  const float* Wmu = (const float*)d_in[23];
  const float* bmu = (const float*)d_in[24];
  const float* Wlv = (const float*)d_in[25];
  const float* blv = (const float*)d_in[26];

  const int A = in_sizes[1];
  const int N = in_sizes[3];
  const int E = in_sizes[5];

  float* ws     = (float*)d_ws;
  float* h      = ws;                          // A*H
  float* agg    = h + (size_t)A * H;           // A*H (reused as k after layers)
  float* vbuf   = agg + (size_t)A * H;         // A*H
  float* dbuf   = vbuf + (size_t)A * H;        // E
  float* qbuf   = dbuf + (size_t)E;            // N*H
  float* pooled = qbuf + (size_t)N * H;        // N*H
  int*   starts = (int*)(pooled + (size_t)N * H);  // N

  k_init_h<<<(A * H + 255) / 256, 256, 0, stream>>>(atom_embed, residue_embed,
                                                    atype, ridx, rtype, h, A);
  k_dist<<<(E + 255) / 256, 256, 0, stream>>>(coords, esrc, edst, dbuf, E);
  k_starts<<<(A + 255) / 256, 256, 0, stream>>>(ridx, starts, A);

  for (int l = 0; l < 3; ++l) {
    hipMemsetAsync(agg, 0, (size_t)A * H * sizeof(float), stream);
    k_edge<<<(E + 31) / 32, 256, 0, stream>>>(
        h, dbuf, esrc, edst,
        We1 + (size_t)l * 272 * H, be1 + (size_t)l * H,
        We2 + (size_t)l * H * H,   be2 + (size_t)l * H, agg, E);
    k_node<<<(A + 31) / 32, 256, 0, stream>>>(
        h, agg,
        Wh1 + (size_t)l * 256 * H, bh1 + (size_t)l * H,
        Wh2 + (size_t)l * H * H,   bh2 + (size_t)l * H, A);
  }

  k_q<<<(N * H + 255) / 256, 256, 0, stream>>>(residue_embed, rtype, Wq, bq, qbuf, N);
  float* kbuf = agg;  // reuse
  k_linear<<<(A + 31) / 32, 256, 0, stream>>>(h, Wk, bk, kbuf, A);
  k_linear<<<(A + 31) / 32, 256, 0, stream>>>(h, Wv, bv, vbuf, A);
  k_pool<<<(N + 3) / 4, 256, 0, stream>>>(qbuf, kbuf, vbuf, starts, apr, pooled, N);
  k_head<<<(N * LATD + 255) / 256, 256, 0, stream>>>(pooled, Wmu, bmu, Wlv, blv,
                                                     (float*)d_out, N);
}

// Round 3
// 1324.112 us; speedup vs baseline: 3.8829x; 3.8829x over previous
//
#include <hip/hip_runtime.h>
#include <hip/hip_bf16.h>

#define H 128
#define RB 16
#define LATD 32

typedef __attribute__((ext_vector_type(8))) _Float16 half8t;        // 8 fp16
typedef __attribute__((ext_vector_type(8))) unsigned short u16x8;   // 16B copy unit
typedef __attribute__((ext_vector_type(4))) float f32x4;

__device__ __forceinline__ float silu_f(float x) {
  return x / (1.0f + __expf(-x));
}
__device__ __forceinline__ unsigned short f16u(float x) {
  _Float16 hh = (_Float16)x;
  return *(unsigned short*)&hh;
}

// ---------------- f32 4x4 register-blocked microkernel ---------------------
template<int K>
__device__ __forceinline__ void mm4x4(const float* X0, int ldx,
                                      const float* __restrict__ W, int c0,
                                      float acc[4][4]) {
  #pragma unroll 4
  for (int k = 0; k < K; k += 4) {
    float4 xv[4], w4[4];
    #pragma unroll
    for (int rr = 0; rr < 4; ++rr) xv[rr] = *(const float4*)(X0 + rr * ldx + k);
    #pragma unroll
    for (int kk = 0; kk < 4; ++kk) w4[kk] = *(const float4*)(W + (size_t)(k + kk) * H + c0);
    const float* x = (const float*)xv;
    const float* w = (const float*)w4;
    #pragma unroll
    for (int rr = 0; rr < 4; ++rr)
      #pragma unroll
      for (int cc = 0; cc < 4; ++cc)
        acc[rr][cc] += x[rr*4+0]*w[cc] + x[rr*4+1]*w[4+cc] +
                       x[rr*4+2]*w[8+cc] + x[rr*4+3]*w[12+cc];
  }
}

__global__ void k_init_h(const float* __restrict__ atom_embed,
                         const float* __restrict__ residue_embed,
                         const int* __restrict__ atype,
                         const int* __restrict__ ridx,
                         const int* __restrict__ rtype,
                         float* __restrict__ h, unsigned short* __restrict__ hb, int A) {
  int i = blockIdx.x * blockDim.x + threadIdx.x;
  if (i >= A * H) return;
  int a = i >> 7, j = i & 127;
  float v = atom_embed[atype[a] * H + j] + residue_embed[rtype[ridx[a]] * H + j];
  h[i] = v;
  hb[i] = f16u(v);
}

__global__ void k_dist(const float* __restrict__ coords,
                       const int* __restrict__ esrc, const int* __restrict__ edst,
                       float* __restrict__ dbuf, int E) {
  int e = blockIdx.x * blockDim.x + threadIdx.x;
  if (e >= E) return;
  int s = esrc[e], t = edst[e];
  float dx = coords[3*s+0] - coords[3*t+0];
  float dy = coords[3*s+1] - coords[3*t+1];
  float dz = coords[3*s+2] - coords[3*t+2];
  dbuf[e] = sqrtf(dx*dx + dy*dy + dz*dz);
}

__global__ void k_starts(const int* __restrict__ ridx, int* __restrict__ starts, int A) {
  int a = blockIdx.x * blockDim.x + threadIdx.x;
  if (a >= A) return;
  if (a == 0 || ridx[a] != ridx[a-1]) starts[ridx[a]] = a;
}

// ---------------- counting sort of edges by dst ----------------------------
__global__ void k_hist(const int* __restrict__ edst, int* __restrict__ cnt, int E) {
  int e = blockIdx.x * blockDim.x + threadIdx.x;
  if (e < E) atomicAdd(&cnt[edst[e]], 1);
}

__global__ __launch_bounds__(1024) void k_scan(const int* __restrict__ cnt,
                                               int* __restrict__ cursor, int A) {
  __shared__ int buf[1024];
  __shared__ int carry;
  int tid = threadIdx.x;
  if (tid == 0) carry = 0;
  __syncthreads();
  int tiles = (A + 1023) >> 10;
  for (int t = 0; t < tiles; ++t) {
    int i = t * 1024 + tid;
    int v = (i < A) ? cnt[i] : 0;
    buf[tid] = v;
    __syncthreads();
    #pragma unroll
    for (int off = 1; off < 1024; off <<= 1) {
      int nv = (tid >= off) ? buf[tid - off] : 0;
      __syncthreads();
      buf[tid] += nv;
      __syncthreads();
    }
    if (i < A) cursor[i] = carry + buf[tid] - v;   // exclusive
    __syncthreads();
    if (tid == 0) carry += buf[1023];
    __syncthreads();
  }
}

__global__ void k_scatter(const int* __restrict__ edst, int* __restrict__ cursor,
                          int* __restrict__ eperm, int E) {
  int e = blockIdx.x * blockDim.x + threadIdx.x;
  if (e >= E) return;
  int p = atomicAdd(&cursor[edst[e]], 1);
  eperm[p] = e;
}

// ---------------- weight packing: per-lane-contiguous B fragments ----------
// layout wp: [We1p 3x36864][We2p 3x16384] (fp16 ushort bits)
// region idx: i=idx&7, lane=(idx>>3)&63, ct=(idx>>9)&7, kt=idx>>12
// value = W[kt*32+(lane>>4)*8+i][ct*16+(lane&15)]  (0 if k >= Korig)
__device__ __forceinline__ void pack_one(const float* __restrict__ src, int Korig,
                                         unsigned short* __restrict__ dst, int idx) {
  int i = idx & 7, lane = (idx >> 3) & 63, ct = (idx >> 9) & 7, kt = idx >> 12;
  int k = kt * 32 + ((lane >> 4) * 8) + i;
  int c = ct * 16 + (lane & 15);
  float v = (k < Korig) ? src[(size_t)k * H + c] : 0.0f;
  dst[idx] = f16u(v);
}

__global__ void k_pack(const float* __restrict__ We1, const float* __restrict__ We2,
                       unsigned short* __restrict__ wp) {
  int t = blockIdx.x * blockDim.x + threadIdx.x;
  if (t >= 159744) return;
  if (t < 110592) {            // We1p: 3 x [9][8][64][8], Korig=272
    int layer = t / 36864, idx = t % 36864;
    pack_one(We1 + (size_t)layer * 272 * H, 272, wp + (size_t)layer * 36864, idx);
  } else {                     // We2p: 3 x [4][8][64][8], Korig=128
    int u = t - 110592; int layer = u / 16384, idx = u % 16384;
    pack_one(We2 + (size_t)layer * 128 * H, 128, wp + 110592 + (size_t)layer * 16384, idx);
  }
}

// ---------------- edge MLP: fp16 MFMA + segmented reduce -------------------
// 64 dst-sorted edges / block, 256 threads (4 waves).
// X: [h_src(128) | h_dst(128) | rbf(16) | zeropad(16)] fp16, K=288 (9 ktiles)
#define XS 296    // X row stride in fp16 (592B: 16B-aligned, slot step odd)
#define M1S 136   // M1 row stride (272B)
#define M2S 132   // M2 f32 row stride

__global__ __launch_bounds__(256) void k_edge_mfma(
    const unsigned short* __restrict__ hb, const float* __restrict__ dbuf,
    const int* __restrict__ esrc, const int* __restrict__ edst,
    const int* __restrict__ eperm,
    const unsigned short* __restrict__ W1p, const float* __restrict__ be1,
    const unsigned short* __restrict__ W2p, const float* __restrict__ be2,
    float* __restrict__ agg, int E) {
  __shared__ __align__(16) unsigned short Xs[64 * XS];    // 37888 B
  __shared__ __align__(16) unsigned short M1s[64 * M1S];  // 17408 B
  __shared__ int dstv[64];
  float* M2s = (float*)Xs;  // alias X (X dead after mm1 barrier); 33792 <= 37888

  const int tid = threadIdx.x;
  const int e0 = blockIdx.x * 64;
  // ---- load: 4 threads per edge row ----
  {
    const int r = tid >> 2, qt = tid & 3;
    int e = e0 + r;
    int ec = (e < E) ? e : (E - 1);
    int es = eperm[ec];
    int s = esrc[es], t = edst[es];
    if (qt == 0) dstv[r] = (e < E) ? t : -1;
    const u16x8* hs = (const u16x8*)(hb + (size_t)s * H);
    const u16x8* ht = (const u16x8*)(hb + (size_t)t * H);
    u16x8* xr = (u16x8*)&Xs[r * XS];
    #pragma unroll
    for (int i = 0; i < 4; ++i) xr[qt*4 + i] = hs[qt*4 + i];
    #pragma unroll
    for (int i = 0; i < 4; ++i) xr[16 + qt*4 + i] = ht[qt*4 + i];
    if (qt < 2) {            // rbf cols 256..271
      float d = dbuf[es];
      #pragma unroll
      for (int i = 0; i < 8; ++i) {
        int j = qt * 8 + i;
        float dd = d - (float)j * (5.0f / 15.0f);
        Xs[r * XS + 256 + j] = f16u(__expf(-10.24f * dd * dd));
      }
    } else if (qt == 2) {    // K-pad cols 272..287 must be zero
      #pragma unroll
      for (int i = 0; i < 16; ++i) Xs[r * XS + 272 + i] = 0;
    }
  }
  __syncthreads();

  const int l = tid & 63, wv = tid >> 6;
  const int lr = l & 15, lk = (l >> 4) * 8;
  const int ct0 = wv * 2;
  const int c0 = ct0 * 16 + lr, c1 = c0 + 16;
  const float b1a = be1[c0], b1b = be1[c1];
  const float b2a = be2[c0], b2b = be2[c1];

  // ---- mm1: X(64x288) @ We1p -> M1(64x128), wave owns 2 col-tiles, 4 row-tiles
  f32x4 acc[4][2] = {};
  #pragma unroll
  for (int kt = 0; kt < 9; ++kt) {
    half8t a[4], b[2];
    #pragma unroll
    for (int rt = 0; rt < 4; ++rt)
      a[rt] = *(const half8t*)&Xs[(rt * 16 + lr) * XS + kt * 32 + lk];
    #pragma unroll
    for (int j = 0; j < 2; ++j)
      b[j] = *(const half8t*)&W1p[(((size_t)kt * 8 + ct0 + j) * 64 + l) * 8];
    #pragma unroll
    for (int rt = 0; rt < 4; ++rt)
      #pragma unroll
      for (int j = 0; j < 2; ++j)
        acc[rt][j] = __builtin_amdgcn_mfma_f32_16x16x32_f16(a[rt], b[j], acc[rt][j], 0, 0, 0);
  }
  #pragma unroll
  for (int rt = 0; rt < 4; ++rt)
    #pragma unroll
    for (int j = 0; j < 2; ++j) {
      float bb = j ? b1b : b1a;
      int col = (ct0 + j) * 16 + lr;
      #pragma unroll
      for (int rr = 0; rr < 4; ++rr) {
        int row = rt * 16 + (l >> 4) * 4 + rr;
        M1s[row * M1S + col] = f16u(silu_f(acc[rt][j][rr] + bb));
      }
    }
  __syncthreads();   // X reads done by all waves; M1 ready

  // ---- mm2: M1(64x128) @ We2p -> M2(64x128)
  f32x4 acc2[4][2] = {};
  #pragma unroll
  for (int kt = 0; kt < 4; ++kt) {
    half8t a[4], b[2];
    #pragma unroll
    for (int rt = 0; rt < 4; ++rt)
      a[rt] = *(const half8t*)&M1s[(rt * 16 + lr) * M1S + kt * 32 + lk];
    #pragma unroll
    for (int j = 0; j < 2; ++j)
      b[j] = *(const half8t*)&W2p[(((size_t)kt * 8 + ct0 + j) * 64 + l) * 8];
    #pragma unroll
    for (int rt = 0; rt < 4; ++rt)
      #pragma unroll
      for (int j = 0; j < 2; ++j)
        acc2[rt][j] = __builtin_amdgcn_mfma_f32_16x16x32_f16(a[rt], b[j], acc2[rt][j], 0, 0, 0);
  }
  // write M2 (aliases X: safe — X dead since mm1 barrier; M1 untouched)
  #pragma unroll
  for (int rt = 0; rt < 4; ++rt)
    #pragma unroll
    for (int j = 0; j < 2; ++j) {
      float bb = j ? b2b : b2a;
      int col = (ct0 + j) * 16 + lr;
      #pragma unroll
      for (int rr = 0; rr < 4; ++rr) {
        int row = rt * 16 + (l >> 4) * 4 + rr;
        M2s[row * M2S + col] = silu_f(acc2[rt][j][rr] + bb);
      }
    }
  __syncthreads();

  // ---- segmented scan-reduce over dst runs: one atomic per (run, col)
  if (tid < 128) {
    int col = tid;
    float accv = 0.0f;
    int prev = -1;
    for (int r = 0; r < 64; ++r) {
      int dv = dstv[r];                // uniform across threads -> broadcast
      float v = M2s[r * M2S + col];
      if (dv != prev) {
        if (prev >= 0) atomicAdd(&agg[(size_t)prev * H + col], accv);
        accv = 0.0f;
        prev = dv;
      }
      if (dv >= 0) accv += v;
    }
    if (prev >= 0) atomicAdd(&agg[(size_t)prev * H + col], accv);
  }
}

// ---------------- node MLP: f32 (accuracy), 32 atoms / block ---------------
__global__ __launch_bounds__(256) void k_node(
    float* __restrict__ h, unsigned short* __restrict__ hb,
    const float* __restrict__ agg,
    const float* __restrict__ Wh1, const float* __restrict__ bh1,
    const float* __restrict__ Wh2, const float* __restrict__ bh2, int A) {
  __shared__ float X[32][260];   // [h | agg], 256 used
  __shared__ float U[32][132];
  const int tid = threadIdx.x, lane = tid & 63, wv = tid >> 6;
  const int a0 = blockIdx.x * 32;
  #pragma unroll
  for (int i = 0; i < 8; ++i) {
    int r = wv * 8 + i;
    int a = a0 + r; if (a >= A) a = A - 1;
    X[r][lane]       = h[(size_t)a*H + lane];
    X[r][64 + lane]  = h[(size_t)a*H + 64 + lane];
    X[r][128 + lane] = agg[(size_t)a*H + lane];
    X[r][192 + lane] = agg[(size_t)a*H + 64 + lane];
  }
  __syncthreads();
  const int rowg = tid >> 5, c0 = (tid & 31) * 4;
  float acc[4][4] = {};
  mm4x4<256>(&X[rowg*4][0], 260, Wh1, c0, acc);
  #pragma unroll
  for (int rr = 0; rr < 4; ++rr)
    #pragma unroll
    for (int cc = 0; cc < 4; ++cc)
      U[rowg*4+rr][c0+cc] = silu_f(acc[rr][cc] + bh1[c0+cc]);
  __syncthreads();
  float acc2[4][4] = {};
  mm4x4<128>(&U[rowg*4][0], 132, Wh2, c0, acc2);
  #pragma unroll
  for (int rr = 0; rr < 4; ++rr) {
    int a = a0 + rowg*4 + rr;
    if (a < A)
      #pragma unroll
      for (int cc = 0; cc < 4; ++cc) {
        size_t off = (size_t)a*H + c0 + cc;
        float nh = h[off] + acc2[rr][cc] + bh2[c0+cc];
        h[off] = nh;
        hb[off] = f16u(nh);
      }
  }
}

// ---------------- tail kernels (f32, known-correct) ------------------------
__global__ __launch_bounds__(256) void k_linear(
    const float* __restrict__ in, const float* __restrict__ W,
    const float* __restrict__ b, float* __restrict__ out, int nrows) {
  __shared__ float X[32][132];
  const int tid = threadIdx.x, lane = tid & 63, wv = tid >> 6;
  const int r0 = blockIdx.x * 32;
  #pragma unroll
  for (int i = 0; i < 8; ++i) {
    int r = wv * 8 + i;
    int a = r0 + r; if (a >= nrows) a = nrows - 1;
    X[r][lane]      = in[(size_t)a*H + lane];
    X[r][64 + lane] = in[(size_t)a*H + 64 + lane];
  }
  __syncthreads();
  const int rowg = tid >> 5, c0 = (tid & 31) * 4;
  float acc[4][4] = {};
  mm4x4<128>(&X[rowg*4][0], 132, W, c0, acc);
  #pragma unroll
  for (int rr = 0; rr < 4; ++rr) {
    int a = r0 + rowg*4 + rr;
    if (a < nrows)
      #pragma unroll
      for (int cc = 0; cc < 4; ++cc)
        out[(size_t)a*H + c0 + cc] = acc[rr][cc] + b[c0+cc];
  }
}

__global__ void k_q(const float* __restrict__ residue_embed,
                    const int* __restrict__ rtype,
                    const float* __restrict__ Wq, const float* __restrict__ bq,
                    float* __restrict__ q, int N) {
  int i = blockIdx.x * blockDim.x + threadIdx.x;
  if (i >= N * H) return;
  int r = i >> 7, j = i & 127;
  const float* emb = residue_embed + (size_t)rtype[r] * H;
  float s = bq[j];
  #pragma unroll 4
  for (int k = 0; k < H; ++k) s += emb[k] * Wq[(size_t)k*H + j];
  q[i] = s;
}

__global__ __launch_bounds__(256) void k_pool(
    const float* __restrict__ q, const float* __restrict__ kbuf,
    const float* __restrict__ vbuf, const int* __restrict__ starts,
    const int* __restrict__ apr, float* __restrict__ pooled, int N) {
  int r = blockIdx.x * 4 + (threadIdx.x >> 6);
  if (r >= N) return;
  int lane = threadIdx.x & 63;
  int s0 = starts[r], cnt = apr[r];
  float q0 = q[(size_t)r*H + lane], q1 = q[(size_t)r*H + 64 + lane];
  float myscore = -1e30f;
  for (int i = 0; i < cnt; ++i) {
    size_t a = (size_t)(s0 + i) * H;
    float p = q0 * kbuf[a + lane] + q1 * kbuf[a + 64 + lane];
    #pragma unroll
    for (int off = 32; off; off >>= 1) p += __shfl_xor(p, off);
    if (lane == i) myscore = p * 0.08838834764831845f;
  }
  float val = (lane < cnt) ? myscore : -1e30f;
  float mx = val;
  #pragma unroll
  for (int off = 32; off; off >>= 1) mx = fmaxf(mx, __shfl_xor(mx, off));
  float ex = (lane < cnt) ? __expf(val - mx) : 0.0f;
  float sum = ex;
  #pragma unroll
  for (int off = 32; off; off >>= 1) sum += __shfl_xor(sum, off);
  float w = ex / sum;
  float p0 = 0.f, p1 = 0.f;
  for (int i = 0; i < cnt; ++i) {
    float wi = __shfl(w, i);
    size_t a = (size_t)(s0 + i) * H;
    p0 += wi * vbuf[a + lane];
    p1 += wi * vbuf[a + 64 + lane];
  }
  pooled[(size_t)r*H + lane] = p0;
  pooled[(size_t)r*H + 64 + lane] = p1;
}

__global__ void k_head(const float* __restrict__ pooled,
                       const float* __restrict__ Wmu, const float* __restrict__ bmu,
                       const float* __restrict__ Wlv, const float* __restrict__ blv,
                       float* __restrict__ out, int N) {
  int i = blockIdx.x * blockDim.x + threadIdx.x;
  if (i >= N * LATD) return;
  int r = i >> 5, j = i & 31;
  const float* p = pooled + (size_t)r * H;
  float smu = 0.f, slv = 0.f;
  #pragma unroll 4
  for (int k = 0; k < H; ++k) {
    float pv = p[k];
    smu += pv * Wmu[(size_t)k*LATD + j];
    slv += pv * Wlv[(size_t)k*LATD + j];
  }
  smu += bmu[j];
  slv += blv[j];
  slv = fminf(fmaxf(slv, -10.0f), 2.0f);
  out[i] = smu;
  out[(size_t)N*LATD + i] = slv;
}

extern "C" void kernel_launch(void* const* d_in, const int* in_sizes, int n_in,
                              void* d_out, int out_size, void* d_ws, size_t ws_size,
                              hipStream_t stream) {
  const float* coords        = (const float*)d_in[0];
  const int*   atype         = (const int*)d_in[1];
  const int*   ridx          = (const int*)d_in[2];
  const int*   rtype         = (const int*)d_in[3];
  const int*   apr           = (const int*)d_in[4];
  const int*   esrc          = (const int*)d_in[5];
  const int*   edst          = (const int*)d_in[6];
  const float* atom_embed    = (const float*)d_in[7];
  const float* residue_embed = (const float*)d_in[8];
  const float* We1 = (const float*)d_in[9];
  const float* be1 = (const float*)d_in[10];
  const float* We2 = (const float*)d_in[11];
  const float* be2 = (const float*)d_in[12];
  const float* Wh1 = (const float*)d_in[13];
  const float* bh1 = (const float*)d_in[14];
  const float* Wh2 = (const float*)d_in[15];
  const float* bh2 = (const float*)d_in[16];
  const float* Wq  = (const float*)d_in[17];
  const float* bq  = (const float*)d_in[18];
  const float* Wk  = (const float*)d_in[19];
  const float* bk  = (const float*)d_in[20];
  const float* Wv  = (const float*)d_in[21];
  const float* bv  = (const float*)d_in[22];
  const float* Wmu = (const float*)d_in[23];
  const float* bmu = (const float*)d_in[24];
  const float* Wlv = (const float*)d_in[25];
  const float* blv = (const float*)d_in[26];

  const int A = in_sizes[1];
  const int N = in_sizes[3];
  const int E = in_sizes[5];

  float* ws     = (float*)d_ws;
  float* h      = ws;                              // A*H f32
  float* agg    = h + (size_t)A * H;               // A*H f32
  float* vbuf   = agg + (size_t)A * H;             // A*H f32
  float* dbuf   = vbuf + (size_t)A * H;            // E f32
  float* qbuf   = dbuf + (size_t)E;                // N*H
  float* pooled = qbuf + (size_t)N * H;            // N*H
  int*   starts = (int*)(pooled + (size_t)N * H);  // N
  unsigned short* hbuf = (unsigned short*)(starts + N);  // A*H fp16
  int*   eperm  = (int*)(hbuf + (size_t)A * H);    // E
  int*   cnt    = eperm + (size_t)E;               // A
  int*   cursor = cnt + A;                         // A
  unsigned short* wp = (unsigned short*)(cursor + A);    // 159744 fp16

  k_init_h<<<(A * H + 255) / 256, 256, 0, stream>>>(atom_embed, residue_embed,
                                                    atype, ridx, rtype, h, hbuf, A);
  k_dist<<<(E + 255) / 256, 256, 0, stream>>>(coords, esrc, edst, dbuf, E);
  k_starts<<<(A + 255) / 256, 256, 0, stream>>>(ridx, starts, A);
  k_pack<<<(159744 + 255) / 256, 256, 0, stream>>>(We1, We2, wp);

  // counting sort of edges by dst
  hipMemsetAsync(cnt, 0, (size_t)A * sizeof(int), stream);
  k_hist<<<(E + 255) / 256, 256, 0, stream>>>(edst, cnt, E);
  k_scan<<<1, 1024, 0, stream>>>(cnt, cursor, A);
  k_scatter<<<(E + 255) / 256, 256, 0, stream>>>(edst, cursor, eperm, E);

  for (int l = 0; l < 3; ++l) {
    hipMemsetAsync(agg, 0, (size_t)A * H * sizeof(float), stream);
    k_edge_mfma<<<(E + 63) / 64, 256, 0, stream>>>(
        hbuf, dbuf, esrc, edst, eperm,
        wp + (size_t)l * 36864,          be1 + (size_t)l * H,
        wp + 110592 + (size_t)l * 16384, be2 + (size_t)l * H, agg, E);
    k_node<<<(A + 31) / 32, 256, 0, stream>>>(
        h, hbuf, agg,
        Wh1 + (size_t)l * 256 * H, bh1 + (size_t)l * H,
        Wh2 + (size_t)l * H * H,   bh2 + (size_t)l * H, A);
  }

  k_q<<<(N * H + 255) / 256, 256, 0, stream>>>(residue_embed, rtype, Wq, bq, qbuf, N);
  float* kbuf = agg;  // reuse
  k_linear<<<(A + 31) / 32, 256, 0, stream>>>(h, Wk, bk, kbuf, A);
  k_linear<<<(A + 31) / 32, 256, 0, stream>>>(h, Wv, bv, vbuf, A);
  k_pool<<<(N + 3) / 4, 256, 0, stream>>>(qbuf, kbuf, vbuf, starts, apr, pooled, N);
  k_head<<<(N * LATD + 255) / 256, 256, 0, stream>>>(pooled, Wmu, bmu, Wlv, blv,
                                                     (float*)d_out, N);
}

// Round 4
// 814.134 us; speedup vs baseline: 6.3152x; 1.6264x over previous
//
#include <hip/hip_runtime.h>
#include <hip/hip_bf16.h>

#define H 128
#define LATD 32

typedef __attribute__((ext_vector_type(8))) _Float16 half8t;        // 8 fp16
typedef __attribute__((ext_vector_type(8))) unsigned short u16x8;   // 16B copy unit
typedef __attribute__((ext_vector_type(4))) float f32x4;

// packed-weight region offsets (u16 elements)
#define OFF_RBF 0         // 3 x [1kt][8ct][64][8]   (We1 rows 256..271, zero-padded K=32)
#define OFF_W2  12288     // 3 x [4kt][8ct][64][8]   (We2)
#define OFF_PROJ 61440    // 3 x [4kt][16ct][64][8]  ([We1_src | We1_dst] 128x256)
#define OFF_H1  159744    // 3 x [8kt][8ct][64][8]   (Wh1)
#define OFF_H2  258048    // 3 x [4kt][8ct][64][8]   (Wh2)
#define WP_TOTAL 307200

__device__ __forceinline__ float silu_f(float x) {
  return x / (1.0f + __expf(-x));
}
__device__ __forceinline__ unsigned short f16u(float x) {
  _Float16 hh = (_Float16)x;
  return *(unsigned short*)&hh;
}

// ---------------- f32 4x4 register-blocked microkernel (tail) --------------
template<int K>
__device__ __forceinline__ void mm4x4(const float* X0, int ldx,
                                      const float* __restrict__ W, int c0,
                                      float acc[4][4]) {
  #pragma unroll 4
  for (int k = 0; k < K; k += 4) {
    float4 xv[4], w4[4];
    #pragma unroll
    for (int rr = 0; rr < 4; ++rr) xv[rr] = *(const float4*)(X0 + rr * ldx + k);
    #pragma unroll
    for (int kk = 0; kk < 4; ++kk) w4[kk] = *(const float4*)(W + (size_t)(k + kk) * H + c0);
    const float* x = (const float*)xv;
    const float* w = (const float*)w4;
    #pragma unroll
    for (int rr = 0; rr < 4; ++rr)
      #pragma unroll
      for (int cc = 0; cc < 4; ++cc)
        acc[rr][cc] += x[rr*4+0]*w[cc] + x[rr*4+1]*w[4+cc] +
                       x[rr*4+2]*w[8+cc] + x[rr*4+3]*w[12+cc];
  }
}

__global__ void k_init_h(const float* __restrict__ atom_embed,
                         const float* __restrict__ residue_embed,
                         const int* __restrict__ atype,
                         const int* __restrict__ ridx,
                         const int* __restrict__ rtype,
                         float* __restrict__ h, unsigned short* __restrict__ hb, int A) {
  int i = blockIdx.x * blockDim.x + threadIdx.x;
  if (i >= A * H) return;
  int a = i >> 7, j = i & 127;
  float v = atom_embed[atype[a] * H + j] + residue_embed[rtype[ridx[a]] * H + j];
  h[i] = v;
  hb[i] = f16u(v);
}

__global__ void k_dist(const float* __restrict__ coords,
                       const int* __restrict__ esrc, const int* __restrict__ edst,
                       float* __restrict__ dbuf, int E) {
  int e = blockIdx.x * blockDim.x + threadIdx.x;
  if (e >= E) return;
  int s = esrc[e], t = edst[e];
  float dx = coords[3*s+0] - coords[3*t+0];
  float dy = coords[3*s+1] - coords[3*t+1];
  float dz = coords[3*s+2] - coords[3*t+2];
  dbuf[e] = sqrtf(dx*dx + dy*dy + dz*dz);
}

__global__ void k_starts(const int* __restrict__ ridx, int* __restrict__ starts, int A) {
  int a = blockIdx.x * blockDim.x + threadIdx.x;
  if (a >= A) return;
  if (a == 0 || ridx[a] != ridx[a-1]) starts[ridx[a]] = a;
}

// ---------------- counting sort of edges by dst ----------------------------
__global__ void k_hist(const int* __restrict__ edst, int* __restrict__ cnt, int E) {
  int e = blockIdx.x * blockDim.x + threadIdx.x;
  if (e < E) atomicAdd(&cnt[edst[e]], 1);
}

__global__ __launch_bounds__(1024) void k_scan(const int* __restrict__ cnt,
                                               int* __restrict__ cursor, int A) {
  __shared__ int buf[1024];
  __shared__ int carry;
  int tid = threadIdx.x;
  if (tid == 0) carry = 0;
  __syncthreads();
  int tiles = (A + 1023) >> 10;
  for (int t = 0; t < tiles; ++t) {
    int i = t * 1024 + tid;
    int v = (i < A) ? cnt[i] : 0;
    buf[tid] = v;
    __syncthreads();
    #pragma unroll
    for (int off = 1; off < 1024; off <<= 1) {
      int nv = (tid >= off) ? buf[tid - off] : 0;
      __syncthreads();
      buf[tid] += nv;
      __syncthreads();
    }
    if (i < A) cursor[i] = carry + buf[tid] - v;   // exclusive
    __syncthreads();
    if (tid == 0) carry += buf[1023];
    __syncthreads();
  }
}

__global__ void k_scatter(const int* __restrict__ edst, int* __restrict__ cursor,
                          int* __restrict__ eperm, int E) {
  int e = blockIdx.x * blockDim.x + threadIdx.x;
  if (e >= E) return;
  int p = atomicAdd(&cursor[edst[e]], 1);
  eperm[p] = e;
}

// ---------------- weight packing into per-lane-contiguous B fragments ------
__global__ void k_pack(const float* __restrict__ We1, const float* __restrict__ We2,
                       const float* __restrict__ Wh1, const float* __restrict__ Wh2,
                       unsigned short* __restrict__ wp) {
  int t = blockIdx.x * blockDim.x + threadIdx.x;
  if (t >= WP_TOTAL) return;
  if (t < OFF_W2) {                      // rbf: We1 rows 256..271, K padded to 32
    int u = t - OFF_RBF; int layer = u / 4096, idx = u % 4096;
    int i = idx & 7, lane = (idx >> 3) & 63, ct = (idx >> 9) & 7;
    int k = ((lane >> 4) * 8) + i;
    int c = ct * 16 + (lane & 15);
    const float* src = We1 + (size_t)layer * 272 * H;
    wp[t] = f16u(k < 16 ? src[(size_t)(256 + k) * H + c] : 0.0f);
  } else if (t < OFF_PROJ) {             // We2 128x128
    int u = t - OFF_W2; int layer = u / 16384, idx = u % 16384;
    int i = idx & 7, lane = (idx >> 3) & 63, ct = (idx >> 9) & 7, kt = idx >> 12;
    int k = kt * 32 + (lane >> 4) * 8 + i, c = ct * 16 + (lane & 15);
    const float* src = We2 + (size_t)layer * 128 * H;
    wp[t] = f16u(src[(size_t)k * H + c]);
  } else if (t < OFF_H1) {               // proj: [We1_src | We1_dst] 128x256
    int u = t - OFF_PROJ; int layer = u / 32768, idx = u % 32768;
    int i = idx & 7, lane = (idx >> 3) & 63, ct = (idx >> 9) & 15, kt = idx >> 13;
    int k = kt * 32 + (lane >> 4) * 8 + i, c = ct * 16 + (lane & 15);
    const float* src = We1 + (size_t)layer * 272 * H;
    float v = (c < 128) ? src[(size_t)k * H + c] : src[(size_t)(128 + k) * H + (c - 128)];
    wp[t] = f16u(v);
  } else if (t < OFF_H2) {               // Wh1 256x128
    int u = t - OFF_H1; int layer = u / 32768, idx = u % 32768;
    int i = idx & 7, lane = (idx >> 3) & 63, ct = (idx >> 9) & 7, kt = idx >> 12;
    int k = kt * 32 + (lane >> 4) * 8 + i, c = ct * 16 + (lane & 15);
    const float* src = Wh1 + (size_t)layer * 256 * H;
    wp[t] = f16u(src[(size_t)k * H + c]);
  } else {                               // Wh2 128x128
    int u = t - OFF_H2; int layer = u / 16384, idx = u % 16384;
    int i = idx & 7, lane = (idx >> 3) & 63, ct = (idx >> 9) & 7, kt = idx >> 12;
    int k = kt * 32 + (lane >> 4) * 8 + i, c = ct * 16 + (lane & 15);
    const float* src = Wh2 + (size_t)layer * 128 * H;
    wp[t] = f16u(src[(size_t)k * H + c]);
  }
}

// ---------------- dense pre-projection: Ph = hb @ [We1_src|We1_dst] --------
// 64 atoms/block, 256 threads; no LDS (A-frags straight from global, L1-reused).
__global__ __launch_bounds__(256) void k_proj(
    const unsigned short* __restrict__ hb, const unsigned short* __restrict__ Wp,
    unsigned short* __restrict__ Ph, int A) {
  const int tid = threadIdx.x, l = tid & 63, wv = tid >> 6;
  const int lr = l & 15, lk = (l >> 4) * 8;
  const int a0 = blockIdx.x * 64;
  f32x4 acc[4][4] = {};
  #pragma unroll
  for (int kt = 0; kt < 4; ++kt) {
    half8t a[4], b[4];
    #pragma unroll
    for (int rt = 0; rt < 4; ++rt) {
      int row = a0 + rt * 16 + lr; if (row >= A) row = A - 1;
      a[rt] = *(const half8t*)&hb[(size_t)row * H + kt * 32 + lk];
    }
    #pragma unroll
    for (int ci = 0; ci < 4; ++ci)
      b[ci] = *(const half8t*)&Wp[(((size_t)kt * 16 + wv * 4 + ci) * 64 + l) * 8];
    #pragma unroll
    for (int rt = 0; rt < 4; ++rt)
      #pragma unroll
      for (int ci = 0; ci < 4; ++ci)
        acc[rt][ci] = __builtin_amdgcn_mfma_f32_16x16x32_f16(a[rt], b[ci], acc[rt][ci], 0, 0, 0);
  }
  #pragma unroll
  for (int rt = 0; rt < 4; ++rt)
    #pragma unroll
    for (int ci = 0; ci < 4; ++ci) {
      int col = (wv * 4 + ci) * 16 + lr;
      #pragma unroll
      for (int rr = 0; rr < 4; ++rr) {
        int row = a0 + rt * 16 + (l >> 4) * 4 + rr;
        if (row < A) Ph[(size_t)row * 256 + col] = f16u(acc[rt][ci][rr]);
      }
    }
}

// ---------------- edge kernel: gather Psum + rbf-MFMA + mm2 + seg-reduce ---
#define PS 136    // Psum stride (fp16): 272B, bank step 4
#define RS 40     // rbf stride (fp16): 80B
#define M1S 136
#define M2SF 130  // M2 f32 stride

__global__ __launch_bounds__(256) void k_edge_mfma(
    const unsigned short* __restrict__ Ph, const float* __restrict__ dbuf,
    const int* __restrict__ esrc, const int* __restrict__ edst,
    const int* __restrict__ eperm,
    const unsigned short* __restrict__ Wr, const float* __restrict__ be1,
    const unsigned short* __restrict__ W2p, const float* __restrict__ be2,
    float* __restrict__ agg, int E) {
  // one contiguous region so M2 (f32) can alias [Psum|rbf|M1]
  __shared__ __align__(16) unsigned short SH[64*PS + 64*RS + 64*M1S];  // 39936 B
  __shared__ int dstv[64];
  unsigned short* Psum = SH;
  unsigned short* rbfs = SH + 64 * PS;
  unsigned short* M1s  = SH + 64 * (PS + RS);
  float* M2s = (float*)SH;   // 64*130*4 = 33280 B <= 39936

  const int tid = threadIdx.x;
  const int e0 = blockIdx.x * 64;
  // ---- stage: 4 threads per edge row ----
  {
    const int r = tid >> 2, qt = tid & 3;
    int e = e0 + r;
    int ec = (e < E) ? e : (E - 1);
    int es = eperm[ec];
    int s = esrc[es], t = edst[es];
    if (qt == 0) dstv[r] = (e < E) ? t : -1;
    const half8t* ps = (const half8t*)(Ph + (size_t)s * 256);        // src proj
    const half8t* pt = (const half8t*)(Ph + (size_t)t * 256 + 128);  // dst proj
    half8t* pr = (half8t*)&Psum[r * PS];
    #pragma unroll
    for (int i = 0; i < 4; ++i)
      pr[qt * 4 + i] = ps[qt * 4 + i] + pt[qt * 4 + i];   // v_pk_add_f16
    if (qt < 2) {
      float d = dbuf[es];
      #pragma unroll
      for (int i = 0; i < 8; ++i) {
        int j = qt * 8 + i;
        float dd = d - (float)j * (5.0f / 15.0f);
        rbfs[r * RS + j] = f16u(__expf(-10.24f * dd * dd));
      }
    } else if (qt == 2) {   // K-pad 16..31 must be zero
      #pragma unroll
      for (int i = 0; i < 16; ++i) rbfs[r * RS + 16 + i] = 0;
    }
  }
  __syncthreads();

  const int l = tid & 63, wv = tid >> 6;
  const int lr = l & 15, lk = (l >> 4) * 8;
  const int ct0 = wv * 2;
  const int c0 = ct0 * 16 + lr, c1 = c0 + 16;
  const float b1a = be1[c0], b1b = be1[c1];
  const float b2a = be2[c0], b2b = be2[c1];

  // ---- rbf MFMA (1 k-tile) ----
  f32x4 acc[4][2] = {};
  {
    half8t bR[2];
    #pragma unroll
    for (int j = 0; j < 2; ++j)
      bR[j] = *(const half8t*)&Wr[(((size_t)(ct0 + j)) * 64 + l) * 8];
    #pragma unroll
    for (int rt = 0; rt < 4; ++rt) {
      half8t aR = *(const half8t*)&rbfs[(rt * 16 + lr) * RS + lk];
      #pragma unroll
      for (int j = 0; j < 2; ++j)
        acc[rt][j] = __builtin_amdgcn_mfma_f32_16x16x32_f16(aR, bR[j], acc[rt][j], 0, 0, 0);
    }
  }
  // ---- combine with Psum + bias, silu -> M1 ----
  #pragma unroll
  for (int rt = 0; rt < 4; ++rt)
    #pragma unroll
    for (int j = 0; j < 2; ++j) {
      float bb = j ? b1b : b1a;
      int col = (ct0 + j) * 16 + lr;
      #pragma unroll
      for (int rr = 0; rr < 4; ++rr) {
        int row = rt * 16 + (l >> 4) * 4 + rr;
        float pre = acc[rt][j][rr] + bb +
                    (float)(*(const _Float16*)&Psum[row * PS + col]);
        M1s[row * M1S + col] = f16u(silu_f(pre));
      }
    }
  __syncthreads();

  // ---- mm2: M1(64x128) @ We2 ----
  f32x4 acc2[4][2] = {};
  #pragma unroll
  for (int kt = 0; kt < 4; ++kt) {
    half8t a[4], b[2];
    #pragma unroll
    for (int rt = 0; rt < 4; ++rt)
      a[rt] = *(const half8t*)&M1s[(rt * 16 + lr) * M1S + kt * 32 + lk];
    #pragma unroll
    for (int j = 0; j < 2; ++j)
      b[j] = *(const half8t*)&W2p[(((size_t)kt * 8 + ct0 + j) * 64 + l) * 8];
    #pragma unroll
    for (int rt = 0; rt < 4; ++rt)
      #pragma unroll
      for (int j = 0; j < 2; ++j)
        acc2[rt][j] = __builtin_amdgcn_mfma_f32_16x16x32_f16(a[rt], b[j], acc2[rt][j], 0, 0, 0);
  }
  __syncthreads();   // all Psum/M1 reads done -> safe to overwrite via M2s alias
  #pragma unroll
  for (int rt = 0; rt < 4; ++rt)
    #pragma unroll
    for (int j = 0; j < 2; ++j) {
      float bb = j ? b2b : b2a;
      int col = (ct0 + j) * 16 + lr;
      #pragma unroll
      for (int rr = 0; rr < 4; ++rr) {
        int row = rt * 16 + (l >> 4) * 4 + rr;
        M2s[row * M2SF + col] = silu_f(acc2[rt][j][rr] + bb);
      }
    }
  __syncthreads();

  // ---- segmented reduce over dst runs, 2 row-halves in parallel ----
  {
    int col = tid & 127, hf = tid >> 7;
    int rbeg = hf * 32, rend = rbeg + 32;
    float accv = 0.0f;
    int prev = -1;
    for (int r = rbeg; r < rend; ++r) {
      int dv = dstv[r];
      float v = M2s[r * M2SF + col];
      if (dv != prev) {
        if (prev >= 0) atomicAdd(&agg[(size_t)prev * H + col], accv);
        accv = 0.0f;
        prev = dv;
      }
      if (dv >= 0) accv += v;
    }
    if (prev >= 0) atomicAdd(&agg[(size_t)prev * H + col], accv);
  }
}

// ---------------- node MLP: fp16 MFMA, 32 atoms/block ----------------------
#define NXS 264   // X stride fp16 (528B)

__global__ __launch_bounds__(256) void k_node_mfma(
    float* __restrict__ h, unsigned short* __restrict__ hb,
    const float* __restrict__ agg,
    const unsigned short* __restrict__ W1p, const float* __restrict__ bh1,
    const unsigned short* __restrict__ W2p, const float* __restrict__ bh2, int A) {
  __shared__ __align__(16) unsigned short Xs[32 * NXS];   // 16896 B
  __shared__ __align__(16) unsigned short Us[32 * M1S];   //  8704 B
  const int tid = threadIdx.x;
  const int a0 = blockIdx.x * 32;
  {
    const int r = tid >> 3, oct = tid & 7;   // 8 threads per atom row
    int a = a0 + r; if (a >= A) a = A - 1;
    const u16x8* hr = (const u16x8*)(hb + (size_t)a * H);
    u16x8* xr = (u16x8*)&Xs[r * NXS];
    xr[oct * 2]     = hr[oct * 2];
    xr[oct * 2 + 1] = hr[oct * 2 + 1];
    const float4* ar = (const float4*)(agg + (size_t)a * H);
    u16x8 tmp[2];
    unsigned short* tp = (unsigned short*)tmp;
    #pragma unroll
    for (int i = 0; i < 4; ++i) {
      float4 av = ar[oct * 4 + i];
      tp[i*4+0] = f16u(av.x); tp[i*4+1] = f16u(av.y);
      tp[i*4+2] = f16u(av.z); tp[i*4+3] = f16u(av.w);
    }
    xr[16 + oct * 2]     = tmp[0];
    xr[16 + oct * 2 + 1] = tmp[1];
  }
  __syncthreads();

  const int l = tid & 63, wv = tid >> 6;
  const int lr = l & 15, lk = (l >> 4) * 8;
  const int ct0 = wv * 2;
  const int c0 = ct0 * 16 + lr, c1 = c0 + 16;
  const float b1a = bh1[c0], b1b = bh1[c1];
  const float b2a = bh2[c0], b2b = bh2[c1];

  f32x4 acc[2][2] = {};
  #pragma unroll
  for (int kt = 0; kt < 8; ++kt) {
    half8t a[2], b[2];
    #pragma unroll
    for (int rt = 0; rt < 2; ++rt)
      a[rt] = *(const half8t*)&Xs[(rt * 16 + lr) * NXS + kt * 32 + lk];
    #pragma unroll
    for (int j = 0; j < 2; ++j)
      b[j] = *(const half8t*)&W1p[(((size_t)kt * 8 + ct0 + j) * 64 + l) * 8];
    #pragma unroll
    for (int rt = 0; rt < 2; ++rt)
      #pragma unroll
      for (int j = 0; j < 2; ++j)
        acc[rt][j] = __builtin_amdgcn_mfma_f32_16x16x32_f16(a[rt], b[j], acc[rt][j], 0, 0, 0);
  }
  #pragma unroll
  for (int rt = 0; rt < 2; ++rt)
    #pragma unroll
    for (int j = 0; j < 2; ++j) {
      float bb = j ? b1b : b1a;
      int col = (ct0 + j) * 16 + lr;
      #pragma unroll
      for (int rr = 0; rr < 4; ++rr) {
        int row = rt * 16 + (l >> 4) * 4 + rr;
        Us[row * M1S + col] = f16u(silu_f(acc[rt][j][rr] + bb));
      }
    }
  __syncthreads();

  f32x4 acc2[2][2] = {};
  #pragma unroll
  for (int kt = 0; kt < 4; ++kt) {
    half8t a[2], b[2];
    #pragma unroll
    for (int rt = 0; rt < 2; ++rt)
      a[rt] = *(const half8t*)&Us[(rt * 16 + lr) * M1S + kt * 32 + lk];
    #pragma unroll
    for (int j = 0; j < 2; ++j)
      b[j] = *(const half8t*)&W2p[(((size_t)kt * 8 + ct0 + j) * 64 + l) * 8];
    #pragma unroll
    for (int rt = 0; rt < 2; ++rt)
      #pragma unroll
      for (int j = 0; j < 2; ++j)
        acc2[rt][j] = __builtin_amdgcn_mfma_f32_16x16x32_f16(a[rt], b[j], acc2[rt][j], 0, 0, 0);
  }
  #pragma unroll
  for (int rt = 0; rt < 2; ++rt)
    #pragma unroll
    for (int j = 0; j < 2; ++j) {
      float bb = j ? b2b : b2a;
      int col = (ct0 + j) * 16 + lr;
      #pragma unroll
      for (int rr = 0; rr < 4; ++rr) {
        int row = rt * 16 + (l >> 4) * 4 + rr;
        int a = a0 + row;
        if (a < A) {
          size_t off = (size_t)a * H + col;
          float nh = h[off] + acc2[rt][j][rr] + bb;
          h[off] = nh;
          hb[off] = f16u(nh);
        }
      }
    }
}

// ---------------- tail kernels (f32, known-correct) ------------------------
__global__ __launch_bounds__(256) void k_linear(
    const float* __restrict__ in, const float* __restrict__ W,
    const float* __restrict__ b, float* __restrict__ out, int nrows) {
  __shared__ float X[32][132];
  const int tid = threadIdx.x, lane = tid & 63, wv = tid >> 6;
  const int r0 = blockIdx.x * 32;
  #pragma unroll
  for (int i = 0; i < 8; ++i) {
    int r = wv * 8 + i;
    int a = r0 + r; if (a >= nrows) a = nrows - 1;
    X[r][lane]      = in[(size_t)a*H + lane];
    X[r][64 + lane] = in[(size_t)a*H + 64 + lane];
  }
  __syncthreads();
  const int rowg = tid >> 5, c0 = (tid & 31) * 4;
  float acc[4][4] = {};
  mm4x4<128>(&X[rowg*4][0], 132, W, c0, acc);
  #pragma unroll
  for (int rr = 0; rr < 4; ++rr) {
    int a = r0 + rowg*4 + rr;
    if (a < nrows)
      #pragma unroll
      for (int cc = 0; cc < 4; ++cc)
        out[(size_t)a*H + c0 + cc] = acc[rr][cc] + b[c0+cc];
  }
}

__global__ void k_q(const float* __restrict__ residue_embed,
                    const int* __restrict__ rtype,
                    const float* __restrict__ Wq, const float* __restrict__ bq,
                    float* __restrict__ q, int N) {
  int i = blockIdx.x * blockDim.x + threadIdx.x;
  if (i >= N * H) return;
  int r = i >> 7, j = i & 127;
  const float* emb = residue_embed + (size_t)rtype[r] * H;
  float s = bq[j];
  #pragma unroll 4
  for (int k = 0; k < H; ++k) s += emb[k] * Wq[(size_t)k*H + j];
  q[i] = s;
}

__global__ __launch_bounds__(256) void k_pool(
    const float* __restrict__ q, const float* __restrict__ kbuf,
    const float* __restrict__ vbuf, const int* __restrict__ starts,
    const int* __restrict__ apr, float* __restrict__ pooled, int N) {
  int r = blockIdx.x * 4 + (threadIdx.x >> 6);
  if (r >= N) return;
  int lane = threadIdx.x & 63;
  int s0 = starts[r], cnt = apr[r];
  float q0 = q[(size_t)r*H + lane], q1 = q[(size_t)r*H + 64 + lane];
  float myscore = -1e30f;
  for (int i = 0; i < cnt; ++i) {
    size_t a = (size_t)(s0 + i) * H;
    float p = q0 * kbuf[a + lane] + q1 * kbuf[a + 64 + lane];
    #pragma unroll
    for (int off = 32; off; off >>= 1) p += __shfl_xor(p, off);
    if (lane == i) myscore = p * 0.08838834764831845f;
  }
  float val = (lane < cnt) ? myscore : -1e30f;
  float mx = val;
  #pragma unroll
  for (int off = 32; off; off >>= 1) mx = fmaxf(mx, __shfl_xor(mx, off));
  float ex = (lane < cnt) ? __expf(val - mx) : 0.0f;
  float sum = ex;
  #pragma unroll
  for (int off = 32; off; off >>= 1) sum += __shfl_xor(sum, off);
  float w = ex / sum;
  float p0 = 0.f, p1 = 0.f;
  for (int i = 0; i < cnt; ++i) {
    float wi = __shfl(w, i);
    size_t a = (size_t)(s0 + i) * H;
    p0 += wi * vbuf[a + lane];
    p1 += wi * vbuf[a + 64 + lane];
  }
  pooled[(size_t)r*H + lane] = p0;
  pooled[(size_t)r*H + 64 + lane] = p1;
}

__global__ void k_head(const float* __restrict__ pooled,
                       const float* __restrict__ Wmu, const float* __restrict__ bmu,
                       const float* __restrict__ Wlv, const float* __restrict__ blv,
                       float* __restrict__ out, int N) {
  int i = blockIdx.x * blockDim.x + threadIdx.x;
  if (i >= N * LATD) return;
  int r = i >> 5, j = i & 31;
  const float* p = pooled + (size_t)r * H;
  float smu = 0.f, slv = 0.f;
  #pragma unroll 4
  for (int k = 0; k < H; ++k) {
    float pv = p[k];
    smu += pv * Wmu[(size_t)k*LATD + j];
    slv += pv * Wlv[(size_t)k*LATD + j];
  }
  smu += bmu[j];
  slv += blv[j];
  slv = fminf(fmaxf(slv, -10.0f), 2.0f);
  out[i] = smu;
  out[(size_t)N*LATD + i] = slv;
}

extern "C" void kernel_launch(void* const* d_in, const int* in_sizes, int n_in,
                              void* d_out, int out_size, void* d_ws, size_t ws_size,
                              hipStream_t stream) {
  const float* coords        = (const float*)d_in[0];
  const int*   atype         = (const int*)d_in[1];
  const int*   ridx          = (const int*)d_in[2];
  const int*   rtype         = (const int*)d_in[3];
  const int*   apr           = (const int*)d_in[4];
  const int*   esrc          = (const int*)d_in[5];
  const int*   edst          = (const int*)d_in[6];
  const float* atom_embed    = (const float*)d_in[7];
  const float* residue_embed = (const float*)d_in[8];
  const float* We1 = (const float*)d_in[9];
  const float* be1 = (const float*)d_in[10];
  const float* We2 = (const float*)d_in[11];
  const float* be2 = (const float*)d_in[12];
  const float* Wh1 = (const float*)d_in[13];
  const float* bh1 = (const float*)d_in[14];
  const float* Wh2 = (const float*)d_in[15];
  const float* bh2 = (const float*)d_in[16];
  const float* Wq  = (const float*)d_in[17];
  const float* bq  = (const float*)d_in[18];
  const float* Wk  = (const float*)d_in[19];
  const float* bk  = (const float*)d_in[20];
  const float* Wv  = (const float*)d_in[21];
  const float* bv  = (const float*)d_in[22];
  const float* Wmu = (const float*)d_in[23];
  const float* bmu = (const float*)d_in[24];
  const float* Wlv = (const float*)d_in[25];
  const float* blv = (const float*)d_in[26];

  const int A = in_sizes[1];
  const int N = in_sizes[3];
  const int E = in_sizes[5];

  float* ws     = (float*)d_ws;
  float* h      = ws;                              // A*H f32
  float* agg    = h + (size_t)A * H;               // A*H f32
  float* vbuf   = agg + (size_t)A * H;             // A*H f32 (aliases Ph)
  float* dbuf   = vbuf + (size_t)A * H;            // E f32
  float* qbuf   = dbuf + (size_t)E;                // N*H
  float* pooled = qbuf + (size_t)N * H;            // N*H
  int*   starts = (int*)(pooled + (size_t)N * H);  // N
  unsigned short* hbuf = (unsigned short*)(starts + N);  // A*H fp16
  int*   eperm  = (int*)(hbuf + (size_t)A * H);    // E
  int*   cnt    = eperm + (size_t)E;               // A
  int*   cursor = cnt + A;                         // A
  unsigned short* wp = (unsigned short*)(cursor + A);    // WP_TOTAL fp16
  unsigned short* Ph = (unsigned short*)vbuf;      // A*256 fp16 == A*H f32 bytes

  k_init_h<<<(A * H + 255) / 256, 256, 0, stream>>>(atom_embed, residue_embed,
                                                    atype, ridx, rtype, h, hbuf, A);
  k_dist<<<(E + 255) / 256, 256, 0, stream>>>(coords, esrc, edst, dbuf, E);
  k_starts<<<(A + 255) / 256, 256, 0, stream>>>(ridx, starts, A);
  k_pack<<<(WP_TOTAL + 255) / 256, 256, 0, stream>>>(We1, We2, Wh1, Wh2, wp);

  // counting sort of edges by dst
  hipMemsetAsync(cnt, 0, (size_t)A * sizeof(int), stream);
  k_hist<<<(E + 255) / 256, 256, 0, stream>>>(edst, cnt, E);
  k_scan<<<1, 1024, 0, stream>>>(cnt, cursor, A);
  k_scatter<<<(E + 255) / 256, 256, 0, stream>>>(edst, cursor, eperm, E);

  for (int l = 0; l < 3; ++l) {
    hipMemsetAsync(agg, 0, (size_t)A * H * sizeof(float), stream);
    k_proj<<<(A + 63) / 64, 256, 0, stream>>>(
        hbuf, wp + OFF_PROJ + (size_t)l * 32768, Ph, A);
    k_edge_mfma<<<(E + 63) / 64, 256, 0, stream>>>(
        Ph, dbuf, esrc, edst, eperm,
        wp + OFF_RBF + (size_t)l * 4096,  be1 + (size_t)l * H,
        wp + OFF_W2  + (size_t)l * 16384, be2 + (size_t)l * H, agg, E);
    k_node_mfma<<<(A + 31) / 32, 256, 0, stream>>>(
        h, hbuf, agg,
        wp + OFF_H1 + (size_t)l * 32768, bh1 + (size_t)l * H,
        wp + OFF_H2 + (size_t)l * 16384, bh2 + (size_t)l * H, A);
  }

  k_q<<<(N * H + 255) / 256, 256, 0, stream>>>(residue_embed, rtype, Wq, bq, qbuf, N);
  float* kbuf = agg;  // reuse
  k_linear<<<(A + 31) / 32, 256, 0, stream>>>(h, Wk, bk, kbuf, A);
  k_linear<<<(A + 31) / 32, 256, 0, stream>>>(h, Wv, bv, vbuf, A);
  k_pool<<<(N + 3) / 4, 256, 0, stream>>>(qbuf, kbuf, vbuf, starts, apr, pooled, N);
  k_head<<<(N * LATD + 255) / 256, 256, 0, stream>>>(pooled, Wmu, bmu, Wlv, blv,
                                                     (float*)d_out, N);
}

// Round 5
// 789.358 us; speedup vs baseline: 6.5135x; 1.0314x over previous
//
#include <hip/hip_runtime.h>
#include <hip/hip_bf16.h>

#define H 128
#define LATD 32

typedef __attribute__((ext_vector_type(8))) _Float16 half8t;        // 8 fp16
typedef __attribute__((ext_vector_type(4))) _Float16 half4t;        // 4 fp16
typedef __attribute__((ext_vector_type(8))) unsigned short u16x8;   // 16B copy unit
typedef __attribute__((ext_vector_type(4))) float f32x4;

// packed-weight region offsets (u16 elements)
#define OFF_RBF 0         // 3 x [1kt][8ct][64][8]   (We1 rows 256..271, zero-padded K=32)
#define OFF_W2  12288     // 3 x [4kt][8ct][64][8]   (We2)
#define OFF_PROJ 61440    // 3 x [4kt][16ct][64][8]  ([We1_src | We1_dst] 128x256)
#define OFF_H1  159744    // 3 x [8kt][8ct][64][8]   (Wh1)
#define OFF_H2  258048    // 3 x [4kt][8ct][64][8]   (Wh2)
#define WP_TOTAL 307200

__device__ __forceinline__ float silu_f(float x) {
  return x / (1.0f + __expf(-x));
}
__device__ __forceinline__ unsigned short f16u(float x) {
  _Float16 hh = (_Float16)x;
  return *(unsigned short*)&hh;
}

// ---------------- f32 4x4 register-blocked microkernel (tail) --------------
template<int K>
__device__ __forceinline__ void mm4x4(const float* X0, int ldx,
                                      const float* __restrict__ W, int c0,
                                      float acc[4][4]) {
  #pragma unroll 4
  for (int k = 0; k < K; k += 4) {
    float4 xv[4], w4[4];
    #pragma unroll
    for (int rr = 0; rr < 4; ++rr) xv[rr] = *(const float4*)(X0 + rr * ldx + k);
    #pragma unroll
    for (int kk = 0; kk < 4; ++kk) w4[kk] = *(const float4*)(W + (size_t)(k + kk) * H + c0);
    const float* x = (const float*)xv;
    const float* w = (const float*)w4;
    #pragma unroll
    for (int rr = 0; rr < 4; ++rr)
      #pragma unroll
      for (int cc = 0; cc < 4; ++cc)
        acc[rr][cc] += x[rr*4+0]*w[cc] + x[rr*4+1]*w[4+cc] +
                       x[rr*4+2]*w[8+cc] + x[rr*4+3]*w[12+cc];
  }
}

__global__ void k_init_h(const float* __restrict__ atom_embed,
                         const float* __restrict__ residue_embed,
                         const int* __restrict__ atype,
                         const int* __restrict__ ridx,
                         const int* __restrict__ rtype,
                         float* __restrict__ h, unsigned short* __restrict__ hb, int A) {
  int i = blockIdx.x * blockDim.x + threadIdx.x;
  if (i >= A * H) return;
  int a = i >> 7, j = i & 127;
  float v = atom_embed[atype[a] * H + j] + residue_embed[rtype[ridx[a]] * H + j];
  h[i] = v;
  hb[i] = f16u(v);
}

__global__ void k_dist(const float* __restrict__ coords,
                       const int* __restrict__ esrc, const int* __restrict__ edst,
                       float* __restrict__ dbuf, int E) {
  int e = blockIdx.x * blockDim.x + threadIdx.x;
  if (e >= E) return;
  int s = esrc[e], t = edst[e];
  float dx = coords[3*s+0] - coords[3*t+0];
  float dy = coords[3*s+1] - coords[3*t+1];
  float dz = coords[3*s+2] - coords[3*t+2];
  dbuf[e] = sqrtf(dx*dx + dy*dy + dz*dz);
}

__global__ void k_starts(const int* __restrict__ ridx, int* __restrict__ starts, int A) {
  int a = blockIdx.x * blockDim.x + threadIdx.x;
  if (a >= A) return;
  if (a == 0 || ridx[a] != ridx[a-1]) starts[ridx[a]] = a;
}

// ---------------- counting sort of edges by dst ----------------------------
__global__ void k_hist(const int* __restrict__ edst, int* __restrict__ cnt, int E) {
  int e = blockIdx.x * blockDim.x + threadIdx.x;
  if (e < E) atomicAdd(&cnt[edst[e]], 1);
}

__global__ __launch_bounds__(1024) void k_scan(const int* __restrict__ cnt,
                                               int* __restrict__ cursor, int A) {
  __shared__ int buf[1024];
  __shared__ int carry;
  int tid = threadIdx.x;
  if (tid == 0) carry = 0;
  __syncthreads();
  int tiles = (A + 1023) >> 10;
  for (int t = 0; t < tiles; ++t) {
    int i = t * 1024 + tid;
    int v = (i < A) ? cnt[i] : 0;
    buf[tid] = v;
    __syncthreads();
    #pragma unroll
    for (int off = 1; off < 1024; off <<= 1) {
      int nv = (tid >= off) ? buf[tid - off] : 0;
      __syncthreads();
      buf[tid] += nv;
      __syncthreads();
    }
    if (i < A) cursor[i] = carry + buf[tid] - v;   // exclusive
    __syncthreads();
    if (tid == 0) carry += buf[1023];
    __syncthreads();
  }
}

__global__ void k_scatter(const int* __restrict__ edst, int* __restrict__ cursor,
                          int* __restrict__ eperm, int E) {
  int e = blockIdx.x * blockDim.x + threadIdx.x;
  if (e >= E) return;
  int p = atomicAdd(&cursor[edst[e]], 1);
  eperm[p] = e;
}

// ---------------- weight packing into per-lane-contiguous fragments --------
// (same fragment map serves as B-frag for X@W and as A-frag for W^T@X^T)
__global__ void k_pack(const float* __restrict__ We1, const float* __restrict__ We2,
                       const float* __restrict__ Wh1, const float* __restrict__ Wh2,
                       unsigned short* __restrict__ wp) {
  int t = blockIdx.x * blockDim.x + threadIdx.x;
  if (t >= WP_TOTAL) return;
  if (t < OFF_W2) {                      // rbf: We1 rows 256..271, K padded to 32
    int u = t - OFF_RBF; int layer = u / 4096, idx = u % 4096;
    int i = idx & 7, lane = (idx >> 3) & 63, ct = (idx >> 9) & 7;
    int k = ((lane >> 4) * 8) + i;
    int c = ct * 16 + (lane & 15);
    const float* src = We1 + (size_t)layer * 272 * H;
    wp[t] = f16u(k < 16 ? src[(size_t)(256 + k) * H + c] : 0.0f);
  } else if (t < OFF_PROJ) {             // We2 128x128
    int u = t - OFF_W2; int layer = u / 16384, idx = u % 16384;
    int i = idx & 7, lane = (idx >> 3) & 63, ct = (idx >> 9) & 7, kt = idx >> 12;
    int k = kt * 32 + (lane >> 4) * 8 + i, c = ct * 16 + (lane & 15);
    const float* src = We2 + (size_t)layer * 128 * H;
    wp[t] = f16u(src[(size_t)k * H + c]);
  } else if (t < OFF_H1) {               // proj: [We1_src | We1_dst] 128x256
    int u = t - OFF_PROJ; int layer = u / 32768, idx = u % 32768;
    int i = idx & 7, lane = (idx >> 3) & 63, ct = (idx >> 9) & 15, kt = idx >> 13;
    int k = kt * 32 + (lane >> 4) * 8 + i, c = ct * 16 + (lane & 15);
    const float* src = We1 + (size_t)layer * 272 * H;
    float v = (c < 128) ? src[(size_t)k * H + c] : src[(size_t)(128 + k) * H + (c - 128)];
    wp[t] = f16u(v);
  } else if (t < OFF_H2) {               // Wh1 256x128
    int u = t - OFF_H1; int layer = u / 32768, idx = u % 32768;
    int i = idx & 7, lane = (idx >> 3) & 63, ct = (idx >> 9) & 7, kt = idx >> 12;
    int k = kt * 32 + (lane >> 4) * 8 + i, c = ct * 16 + (lane & 15);
    const float* src = Wh1 + (size_t)layer * 256 * H;
    wp[t] = f16u(src[(size_t)k * H + c]);
  } else {                               // Wh2 128x128
    int u = t - OFF_H2; int layer = u / 16384, idx = u % 16384;
    int i = idx & 7, lane = (idx >> 3) & 63, ct = (idx >> 9) & 7, kt = idx >> 12;
    int k = kt * 32 + (lane >> 4) * 8 + i, c = ct * 16 + (lane & 15);
    const float* src = Wh2 + (size_t)layer * 128 * H;
    wp[t] = f16u(src[(size_t)k * H + c]);
  }
}

// ---------------- dense pre-projection: Ph = hb @ [We1_src|We1_dst] --------
__global__ __launch_bounds__(256) void k_proj(
    const unsigned short* __restrict__ hb, const unsigned short* __restrict__ Wp,
    unsigned short* __restrict__ Ph, int A) {
  const int tid = threadIdx.x, l = tid & 63, wv = tid >> 6;
  const int lr = l & 15, lk = (l >> 4) * 8;
  const int a0 = blockIdx.x * 64;
  f32x4 acc[4][4] = {};
  #pragma unroll
  for (int kt = 0; kt < 4; ++kt) {
    half8t a[4], b[4];
    #pragma unroll
    for (int rt = 0; rt < 4; ++rt) {
      int row = a0 + rt * 16 + lr; if (row >= A) row = A - 1;
      a[rt] = *(const half8t*)&hb[(size_t)row * H + kt * 32 + lk];
    }
    #pragma unroll
    for (int ci = 0; ci < 4; ++ci)
      b[ci] = *(const half8t*)&Wp[(((size_t)kt * 16 + wv * 4 + ci) * 64 + l) * 8];
    #pragma unroll
    for (int rt = 0; rt < 4; ++rt)
      #pragma unroll
      for (int ci = 0; ci < 4; ++ci)
        acc[rt][ci] = __builtin_amdgcn_mfma_f32_16x16x32_f16(a[rt], b[ci], acc[rt][ci], 0, 0, 0);
  }
  #pragma unroll
  for (int rt = 0; rt < 4; ++rt)
    #pragma unroll
    for (int ci = 0; ci < 4; ++ci) {
      int col = (wv * 4 + ci) * 16 + lr;
      #pragma unroll
      for (int rr = 0; rr < 4; ++rr) {
        int row = a0 + rt * 16 + (l >> 4) * 4 + rr;
        if (row < A) Ph[(size_t)row * 256 + col] = f16u(acc[rt][ci][rr]);
      }
    }
}

// ---------------- edge kernel (transposed compute: D = W^T @ X^T) ----------
// 64 dst-sorted edges / block, 256 threads (4 waves).
// Wave wv owns feature-tiles {2wv, 2wv+1} x all 4 edge-tiles.
#define PS 136    // Psum stride (fp16): 272B/row, 16B-aligned
#define RS 40     // rbf stride (fp16): 80B/row
#define M1S 136   // M1 stride (fp16)
#define M2SF 132  // M2 f32 stride: 528B/row, 16B-aligned

__global__ __launch_bounds__(256) void k_edge_mfma(
    const unsigned short* __restrict__ Ph, const float* __restrict__ dbuf,
    const int* __restrict__ esrc, const int* __restrict__ edst,
    const int* __restrict__ eperm,
    const unsigned short* __restrict__ Wr, const float* __restrict__ be1,
    const unsigned short* __restrict__ W2p, const float* __restrict__ be2,
    float* __restrict__ agg, int E) {
  // one contiguous region so M2 (f32) can alias [Psum|rbf|M1]
  __shared__ __align__(16) unsigned short SH[64*PS + 64*RS + 64*M1S];  // 39936 B
  __shared__ int dstv[64];
  unsigned short* Psum = SH;
  unsigned short* rbfs = SH + 64 * PS;
  unsigned short* M1s  = SH + 64 * (PS + RS);
  float* M2s = (float*)SH;   // 64*132*4 = 33792 B <= 39936

  const int tid = threadIdx.x;
  const int e0 = blockIdx.x * 64;
  // ---- stage: 4 threads per edge row; Psum[e][c] = Ph_src[c] + Ph_dst[c+128]
  {
    const int r = tid >> 2, qt = tid & 3;
    int e = e0 + r;
    int ec = (e < E) ? e : (E - 1);
    int es = eperm[ec];
    int s = esrc[es], t = edst[es];
    if (qt == 0) dstv[r] = (e < E) ? t : -1;
    const half8t* ps = (const half8t*)(Ph + (size_t)s * 256);        // src proj
    const half8t* pt = (const half8t*)(Ph + (size_t)t * 256 + 128);  // dst proj
    half8t* pr = (half8t*)&Psum[r * PS];
    #pragma unroll
    for (int i = 0; i < 4; ++i)
      pr[qt * 4 + i] = ps[qt * 4 + i] + pt[qt * 4 + i];   // v_pk_add_f16
    if (qt < 2) {
      float d = dbuf[es];
      #pragma unroll
      for (int i = 0; i < 8; ++i) {
        int j = qt * 8 + i;
        float dd = d - (float)j * (5.0f / 15.0f);
        rbfs[r * RS + j] = f16u(__expf(-10.24f * dd * dd));
      }
    } else if (qt == 2) {   // K-pad 16..31 must be zero
      #pragma unroll
      for (int i = 0; i < 16; ++i) rbfs[r * RS + 16 + i] = 0;
    }
  }
  __syncthreads();

  const int l = tid & 63, wv = tid >> 6;
  const int lr = l & 15, lk = (l >> 4) * 8, g4 = (l >> 4) * 4;
  const int ct0 = wv * 2;

  // ---- mm1T: acc[cj][et] = Psum^T (direct b64 read) + We1rbf^T @ rbf^T ----
  f32x4 acc[2][4];
  #pragma unroll
  for (int cj = 0; cj < 2; ++cj) {
    int cbase = (ct0 + cj) * 16 + g4;
    #pragma unroll
    for (int et = 0; et < 4; ++et) {
      half4t p4 = *(const half4t*)&Psum[(et * 16 + lr) * PS + cbase];
      acc[cj][et][0] = (float)p4[0];
      acc[cj][et][1] = (float)p4[1];
      acc[cj][et][2] = (float)p4[2];
      acc[cj][et][3] = (float)p4[3];
    }
  }
  {
    half8t ar[2];
    #pragma unroll
    for (int cj = 0; cj < 2; ++cj)
      ar[cj] = *(const half8t*)&Wr[(((size_t)(ct0 + cj)) * 64 + l) * 8];
    #pragma unroll
    for (int et = 0; et < 4; ++et) {
      half8t br = *(const half8t*)&rbfs[(et * 16 + lr) * RS + lk];
      #pragma unroll
      for (int cj = 0; cj < 2; ++cj)
        acc[cj][et] = __builtin_amdgcn_mfma_f32_16x16x32_f16(ar[cj], br, acc[cj][et], 0, 0, 0);
    }
  }
  // silu(acc + be1) -> M1[e][c] as packed b64
  #pragma unroll
  for (int cj = 0; cj < 2; ++cj) {
    f32x4 b1v = *(const f32x4*)&be1[(ct0 + cj) * 16 + g4];
    #pragma unroll
    for (int et = 0; et < 4; ++et) {
      half4t m4;
      #pragma unroll
      for (int rr = 0; rr < 4; ++rr)
        m4[rr] = (_Float16)silu_f(acc[cj][et][rr] + b1v[rr]);
      *(half4t*)&M1s[(et * 16 + lr) * M1S + (ct0 + cj) * 16 + g4] = m4;
    }
  }
  __syncthreads();

  // ---- mm2T: acc2 = We2^T @ M1^T ----
  f32x4 acc2[2][4] = {};
  #pragma unroll
  for (int kt = 0; kt < 4; ++kt) {
    half8t a2[2], b2[4];
    #pragma unroll
    for (int cj = 0; cj < 2; ++cj)
      a2[cj] = *(const half8t*)&W2p[(((size_t)kt * 8 + ct0 + cj) * 64 + l) * 8];
    #pragma unroll
    for (int et = 0; et < 4; ++et)
      b2[et] = *(const half8t*)&M1s[(et * 16 + lr) * M1S + kt * 32 + lk];
    #pragma unroll
    for (int cj = 0; cj < 2; ++cj)
      #pragma unroll
      for (int et = 0; et < 4; ++et)
        acc2[cj][et] = __builtin_amdgcn_mfma_f32_16x16x32_f16(a2[cj], b2[et], acc2[cj][et], 0, 0, 0);
  }
  __syncthreads();   // all Psum/M1 reads done -> safe to alias-write M2
  #pragma unroll
  for (int cj = 0; cj < 2; ++cj) {
    f32x4 b2v = *(const f32x4*)&be2[(ct0 + cj) * 16 + g4];
    #pragma unroll
    for (int et = 0; et < 4; ++et) {
      f32x4 w;
      #pragma unroll
      for (int rr = 0; rr < 4; ++rr)
        w[rr] = silu_f(acc2[cj][et][rr] + b2v[rr]);
      *(f32x4*)&M2s[(et * 16 + lr) * M2SF + (ct0 + cj) * 16 + g4] = w;
    }
  }
  __syncthreads();

  // ---- segmented reduce over dst runs: thread = (colpair, row-quarter) ----
  {
    int cp = tid & 63, qr = tid >> 6;
    int rbeg = qr * 16, rend = rbeg + 16;
    float a0 = 0.f, a1 = 0.f;
    int prev = -1;
    for (int r = rbeg; r < rend; ++r) {
      int dv = dstv[r];
      float2 v = *(const float2*)&M2s[r * M2SF + cp * 2];
      if (dv != prev) {
        if (prev >= 0) {
          atomicAdd(&agg[(size_t)prev * H + cp * 2], a0);
          atomicAdd(&agg[(size_t)prev * H + cp * 2 + 1], a1);
        }
        a0 = a1 = 0.f;
        prev = dv;
      }
      if (dv >= 0) { a0 += v.x; a1 += v.y; }
    }
    if (prev >= 0) {
      atomicAdd(&agg[(size_t)prev * H + cp * 2], a0);
      atomicAdd(&agg[(size_t)prev * H + cp * 2 + 1], a1);
    }
  }
}

// ---------------- node MLP: fp16 MFMA, 32 atoms/block ----------------------
#define NXS 264   // X stride fp16 (528B)

__global__ __launch_bounds__(256) void k_node_mfma(
    float* __restrict__ h, unsigned short* __restrict__ hb,
    const float* __restrict__ agg,
    const unsigned short* __restrict__ W1p, const float* __restrict__ bh1,
    const unsigned short* __restrict__ W2p, const float* __restrict__ bh2, int A) {
  __shared__ __align__(16) unsigned short Xs[32 * NXS];   // 16896 B
  __shared__ __align__(16) unsigned short Us[32 * M1S];   //  8704 B
  const int tid = threadIdx.x;
  const int a0 = blockIdx.x * 32;
  {
    const int r = tid >> 3, oct = tid & 7;   // 8 threads per atom row
    int a = a0 + r; if (a >= A) a = A - 1;
    const u16x8* hr = (const u16x8*)(hb + (size_t)a * H);
    u16x8* xr = (u16x8*)&Xs[r * NXS];
    xr[oct * 2]     = hr[oct * 2];
    xr[oct * 2 + 1] = hr[oct * 2 + 1];
    const float4* ar = (const float4*)(agg + (size_t)a * H);
    u16x8 tmp[2];
    unsigned short* tp = (unsigned short*)tmp;
    #pragma unroll
    for (int i = 0; i < 4; ++i) {
      float4 av = ar[oct * 4 + i];
      tp[i*4+0] = f16u(av.x); tp[i*4+1] = f16u(av.y);
      tp[i*4+2] = f16u(av.z); tp[i*4+3] = f16u(av.w);
    }
    xr[16 + oct * 2]     = tmp[0];
    xr[16 + oct * 2 + 1] = tmp[1];
  }
  __syncthreads();

  const int l = tid & 63, wv = tid >> 6;
  const int lr = l & 15, lk = (l >> 4) * 8;
  const int ct0 = wv * 2;
  const int c0 = ct0 * 16 + lr, c1 = c0 + 16;
  const float b1a = bh1[c0], b1b = bh1[c1];
  const float b2a = bh2[c0], b2b = bh2[c1];

  f32x4 acc[2][2] = {};
  #pragma unroll
  for (int kt = 0; kt < 8; ++kt) {
    half8t a[2], b[2];
    #pragma unroll
    for (int rt = 0; rt < 2; ++rt)
      a[rt] = *(const half8t*)&Xs[(rt * 16 + lr) * NXS + kt * 32 + lk];
    #pragma unroll
    for (int j = 0; j < 2; ++j)
      b[j] = *(const half8t*)&W1p[(((size_t)kt * 8 + ct0 + j) * 64 + l) * 8];
    #pragma unroll
    for (int rt = 0; rt < 2; ++rt)
      #pragma unroll
      for (int j = 0; j < 2; ++j)
        acc[rt][j] = __builtin_amdgcn_mfma_f32_16x16x32_f16(a[rt], b[j], acc[rt][j], 0, 0, 0);
  }
  #pragma unroll
  for (int rt = 0; rt < 2; ++rt)
    #pragma unroll
    for (int j = 0; j < 2; ++j) {
      float bb = j ? b1b : b1a;
      int col = (ct0 + j) * 16 + lr;
      #pragma unroll
      for (int rr = 0; rr < 4; ++rr) {
        int row = rt * 16 + (l >> 4) * 4 + rr;
        Us[row * M1S + col] = f16u(silu_f(acc[rt][j][rr] + bb));
      }
    }
  __syncthreads();

  f32x4 acc2[2][2] = {};
  #pragma unroll
  for (int kt = 0; kt < 4; ++kt) {
    half8t a[2], b[2];
    #pragma unroll
    for (int rt = 0; rt < 2; ++rt)
      a[rt] = *(const half8t*)&Us[(rt * 16 + lr) * M1S + kt * 32 + lk];
    #pragma unroll
    for (int j = 0; j < 2; ++j)
      b[j] = *(const half8t*)&W2p[(((size_t)kt * 8 + ct0 + j) * 64 + l) * 8];
    #pragma unroll
    for (int rt = 0; rt < 2; ++rt)
      #pragma unroll
      for (int j = 0; j < 2; ++j)
        acc2[rt][j] = __builtin_amdgcn_mfma_f32_16x16x32_f16(a[rt], b[j], acc2[rt][j], 0, 0, 0);
  }
  #pragma unroll
  for (int rt = 0; rt < 2; ++rt)
    #pragma unroll
    for (int j = 0; j < 2; ++j) {
      float bb = j ? b2b : b2a;
      int col = (ct0 + j) * 16 + lr;
      #pragma unroll
      for (int rr = 0; rr < 4; ++rr) {
        int row = rt * 16 + (l >> 4) * 4 + rr;
        int a = a0 + row;
        if (a < A) {
          size_t off = (size_t)a * H + col;
          float nh = h[off] + acc2[rt][j][rr] + bb;
          h[off] = nh;
          hb[off] = f16u(nh);
        }
      }
    }
}

// ---------------- tail kernels (f32, known-correct) ------------------------
__global__ __launch_bounds__(256) void k_linear(
    const float* __restrict__ in, const float* __restrict__ W,
    const float* __restrict__ b, float* __restrict__ out, int nrows) {
  __shared__ float X[32][132];
  const int tid = threadIdx.x, lane = tid & 63, wv = tid >> 6;
  const int r0 = blockIdx.x * 32;
  #pragma unroll
  for (int i = 0; i < 8; ++i) {
    int r = wv * 8 + i;
    int a = r0 + r; if (a >= nrows) a = nrows - 1;
    X[r][lane]      = in[(size_t)a*H + lane];
    X[r][64 + lane] = in[(size_t)a*H + 64 + lane];
  }
  __syncthreads();
  const int rowg = tid >> 5, c0 = (tid & 31) * 4;
  float acc[4][4] = {};
  mm4x4<128>(&X[rowg*4][0], 132, W, c0, acc);
  #pragma unroll
  for (int rr = 0; rr < 4; ++rr) {
    int a = r0 + rowg*4 + rr;
    if (a < nrows)
      #pragma unroll
      for (int cc = 0; cc < 4; ++cc)
        out[(size_t)a*H + c0 + cc] = acc[rr][cc] + b[c0+cc];
  }
}

__global__ void k_q(const float* __restrict__ residue_embed,
                    const int* __restrict__ rtype,
                    const float* __restrict__ Wq, const float* __restrict__ bq,
                    float* __restrict__ q, int N) {
  int i = blockIdx.x * blockDim.x + threadIdx.x;
  if (i >= N * H) return;
  int r = i >> 7, j = i & 127;
  const float* emb = residue_embed + (size_t)rtype[r] * H;
  float s = bq[j];
  #pragma unroll 4
  for (int k = 0; k < H; ++k) s += emb[k] * Wq[(size_t)k*H + j];
  q[i] = s;
}

__global__ __launch_bounds__(256) void k_pool(
    const float* __restrict__ q, const float* __restrict__ kbuf,
    const float* __restrict__ vbuf, const int* __restrict__ starts,
    const int* __restrict__ apr, float* __restrict__ pooled, int N) {
  int r = blockIdx.x * 4 + (threadIdx.x >> 6);
  if (r >= N) return;
  int lane = threadIdx.x & 63;
  int s0 = starts[r], cnt = apr[r];
  float q0 = q[(size_t)r*H + lane], q1 = q[(size_t)r*H + 64 + lane];
  float myscore = -1e30f;
  for (int i = 0; i < cnt; ++i) {
    size_t a = (size_t)(s0 + i) * H;
    float p = q0 * kbuf[a + lane] + q1 * kbuf[a + 64 + lane];
    #pragma unroll
    for (int off = 32; off; off >>= 1) p += __shfl_xor(p, off);
    if (lane == i) myscore = p * 0.08838834764831845f;
  }
  float val = (lane < cnt) ? myscore : -1e30f;
  float mx = val;
  #pragma unroll
  for (int off = 32; off; off >>= 1) mx = fmaxf(mx, __shfl_xor(mx, off));
  float ex = (lane < cnt) ? __expf(val - mx) : 0.0f;
  float sum = ex;
  #pragma unroll
  for (int off = 32; off; off >>= 1) sum += __shfl_xor(sum, off);
  float w = ex / sum;
  float p0 = 0.f, p1 = 0.f;
  for (int i = 0; i < cnt; ++i) {
    float wi = __shfl(w, i);
    size_t a = (size_t)(s0 + i) * H;
    p0 += wi * vbuf[a + lane];
    p1 += wi * vbuf[a + 64 + lane];
  }
  pooled[(size_t)r*H + lane] = p0;
  pooled[(size_t)r*H + 64 + lane] = p1;
}

__global__ void k_head(const float* __restrict__ pooled,
                       const float* __restrict__ Wmu, const float* __restrict__ bmu,
                       const float* __restrict__ Wlv, const float* __restrict__ blv,
                       float* __restrict__ out, int N) {
  int i = blockIdx.x * blockDim.x + threadIdx.x;
  if (i >= N * LATD) return;
  int r = i >> 5, j = i & 31;
  const float* p = pooled + (size_t)r * H;
  float smu = 0.f, slv = 0.f;
  #pragma unroll 4
  for (int k = 0; k < H; ++k) {
    float pv = p[k];
    smu += pv * Wmu[(size_t)k*LATD + j];
    slv += pv * Wlv[(size_t)k*LATD + j];
  }
  smu += bmu[j];
  slv += blv[j];
  slv = fminf(fmaxf(slv, -10.0f), 2.0f);
  out[i] = smu;
  out[(size_t)N*LATD + i] = slv;
}

extern "C" void kernel_launch(void* const* d_in, const int* in_sizes, int n_in,
                              void* d_out, int out_size, void* d_ws, size_t ws_size,
                              hipStream_t stream) {
  const float* coords        = (const float*)d_in[0];
  const int*   atype         = (const int*)d_in[1];
  const int*   ridx          = (const int*)d_in[2];
  const int*   rtype         = (const int*)d_in[3];
  const int*   apr           = (const int*)d_in[4];
  const int*   esrc          = (const int*)d_in[5];
  const int*   edst          = (const int*)d_in[6];
  const float* atom_embed    = (const float*)d_in[7];
  const float* residue_embed = (const float*)d_in[8];
  const float* We1 = (const float*)d_in[9];
  const float* be1 = (const float*)d_in[10];
  const float* We2 = (const float*)d_in[11];
  const float* be2 = (const float*)d_in[12];
  const float* Wh1 = (const float*)d_in[13];
  const float* bh1 = (const float*)d_in[14];
  const float* Wh2 = (const float*)d_in[15];
  const float* bh2 = (const float*)d_in[16];
  const float* Wq  = (const float*)d_in[17];
  const float* bq  = (const float*)d_in[18];
  const float* Wk  = (const float*)d_in[19];
  const float* bk  = (const float*)d_in[20];
  const float* Wv  = (const float*)d_in[21];
  const float* bv  = (const float*)d_in[22];
  const float* Wmu = (const float*)d_in[23];
  const float* bmu = (const float*)d_in[24];
  const float* Wlv = (const float*)d_in[25];
  const float* blv = (const float*)d_in[26];

  const int A = in_sizes[1];
  const int N = in_sizes[3];
  const int E = in_sizes[5];

  float* ws     = (float*)d_ws;
  float* h      = ws;                              // A*H f32
  float* agg    = h + (size_t)A * H;               // A*H f32
  float* vbuf   = agg + (size_t)A * H;             // A*H f32 (aliases Ph)
  float* dbuf   = vbuf + (size_t)A * H;            // E f32
  float* qbuf   = dbuf + (size_t)E;                // N*H
  float* pooled = qbuf + (size_t)N * H;            // N*H
  int*   starts = (int*)(pooled + (size_t)N * H);  // N
  unsigned short* hbuf = (unsigned short*)(starts + N);  // A*H fp16
  int*   eperm  = (int*)(hbuf + (size_t)A * H);    // E
  int*   cnt    = eperm + (size_t)E;               // A
  int*   cursor = cnt + A;                         // A
  unsigned short* wp = (unsigned short*)(cursor + A);    // WP_TOTAL fp16
  unsigned short* Ph = (unsigned short*)vbuf;      // A*256 fp16 == A*H f32 bytes

  k_init_h<<<(A * H + 255) / 256, 256, 0, stream>>>(atom_embed, residue_embed,
                                                    atype, ridx, rtype, h, hbuf, A);
  k_dist<<<(E + 255) / 256, 256, 0, stream>>>(coords, esrc, edst, dbuf, E);
  k_starts<<<(A + 255) / 256, 256, 0, stream>>>(ridx, starts, A);
  k_pack<<<(WP_TOTAL + 255) / 256, 256, 0, stream>>>(We1, We2, Wh1, Wh2, wp);

  // counting sort of edges by dst
  hipMemsetAsync(cnt, 0, (size_t)A * sizeof(int), stream);
  k_hist<<<(E + 255) / 256, 256, 0, stream>>>(edst, cnt, E);
  k_scan<<<1, 1024, 0, stream>>>(cnt, cursor, A);
  k_scatter<<<(E + 255) / 256, 256, 0, stream>>>(edst, cursor, eperm, E);

  for (int l = 0; l < 3; ++l) {
    hipMemsetAsync(agg, 0, (size_t)A * H * sizeof(float), stream);
    k_proj<<<(A + 63) / 64, 256, 0, stream>>>(
        hbuf, wp + OFF_PROJ + (size_t)l * 32768, Ph, A);
    k_edge_mfma<<<(E + 63) / 64, 256, 0, stream>>>(
        Ph, dbuf, esrc, edst, eperm,
        wp + OFF_RBF + (size_t)l * 4096,  be1 + (size_t)l * H,
        wp + OFF_W2  + (size_t)l * 16384, be2 + (size_t)l * H, agg, E);
    k_node_mfma<<<(A + 31) / 32, 256, 0, stream>>>(
        h, hbuf, agg,
        wp + OFF_H1 + (size_t)l * 32768, bh1 + (size_t)l * H,
        wp + OFF_H2 + (size_t)l * 16384, bh2 + (size_t)l * H, A);
  }

  k_q<<<(N * H + 255) / 256, 256, 0, stream>>>(residue_embed, rtype, Wq, bq, qbuf, N);
  float* kbuf = agg;  // reuse
  k_linear<<<(A + 31) / 32, 256, 0, stream>>>(h, Wk, bk, kbuf, A);
  k_linear<<<(A + 31) / 32, 256, 0, stream>>>(h, Wv, bv, vbuf, A);
  k_pool<<<(N + 3) / 4, 256, 0, stream>>>(qbuf, kbuf, vbuf, starts, apr, pooled, N);
  k_head<<<(N * LATD + 255) / 256, 256, 0, stream>>>(pooled, Wmu, bmu, Wlv, blv,
                                                     (float*)d_out, N);
}

// Round 6
// 664.359 us; speedup vs baseline: 7.7390x; 1.1882x over previous
//
#include <hip/hip_runtime.h>
#include <hip/hip_bf16.h>

#define H 128
#define LATD 32

typedef __attribute__((ext_vector_type(8))) _Float16 half8t;        // 8 fp16
typedef __attribute__((ext_vector_type(4))) _Float16 half4t;        // 4 fp16
typedef __attribute__((ext_vector_type(8))) unsigned short u16x8;   // 16B copy unit
typedef __attribute__((ext_vector_type(4))) float f32x4;

// packed-weight region offsets (u16 elements)
#define OFF_RBF 0         // 3 x [1kt][8ct][64][8]   (We1 rows 256..271, zero-padded K=32)
#define OFF_W2  12288     // 3 x [4kt][8ct][64][8]   (We2)
#define OFF_PROJ 61440    // 3 x [4kt][16ct][64][8]  ([We1_src | We1_dst] 128x256)
#define OFF_H1  159744    // 3 x [8kt][8ct][64][8]   (Wh1)
#define OFF_H2  258048    // 3 x [4kt][8ct][64][8]   (Wh2)
#define WP_TOTAL 307200

// silu via native rcp: avoids the IEEE v_div_scale/fmas/fixup sequence
// (~10 VALU per div); rcp err ~1ulp, negligible vs fp16 quantization.
__device__ __forceinline__ float silu_f(float x) {
  return x * __builtin_amdgcn_rcpf(1.0f + __expf(-x));
}
__device__ __forceinline__ unsigned short f16u(float x) {
  _Float16 hh = (_Float16)x;
  return *(unsigned short*)&hh;
}

// ---------------- f32 4x4 register-blocked microkernel (tail) --------------
template<int K>
__device__ __forceinline__ void mm4x4(const float* X0, int ldx,
                                      const float* __restrict__ W, int c0,
                                      float acc[4][4]) {
  #pragma unroll 4
  for (int k = 0; k < K; k += 4) {
    float4 xv[4], w4[4];
    #pragma unroll
    for (int rr = 0; rr < 4; ++rr) xv[rr] = *(const float4*)(X0 + rr * ldx + k);
    #pragma unroll
    for (int kk = 0; kk < 4; ++kk) w4[kk] = *(const float4*)(W + (size_t)(k + kk) * H + c0);
    const float* x = (const float*)xv;
    const float* w = (const float*)w4;
    #pragma unroll
    for (int rr = 0; rr < 4; ++rr)
      #pragma unroll
      for (int cc = 0; cc < 4; ++cc)
        acc[rr][cc] += x[rr*4+0]*w[cc] + x[rr*4+1]*w[4+cc] +
                       x[rr*4+2]*w[8+cc] + x[rr*4+3]*w[12+cc];
  }
}

__global__ void k_init_h(const float* __restrict__ atom_embed,
                         const float* __restrict__ residue_embed,
                         const int* __restrict__ atype,
                         const int* __restrict__ ridx,
                         const int* __restrict__ rtype,
                         float* __restrict__ h, unsigned short* __restrict__ hb, int A) {
  int i = blockIdx.x * blockDim.x + threadIdx.x;
  if (i >= A * H) return;
  int a = i >> 7, j = i & 127;
  float v = atom_embed[atype[a] * H + j] + residue_embed[rtype[ridx[a]] * H + j];
  h[i] = v;
  hb[i] = f16u(v);
}

__global__ void k_dist(const float* __restrict__ coords,
                       const int* __restrict__ esrc, const int* __restrict__ edst,
                       float* __restrict__ dbuf, int E) {
  int e = blockIdx.x * blockDim.x + threadIdx.x;
  if (e >= E) return;
  int s = esrc[e], t = edst[e];
  float dx = coords[3*s+0] - coords[3*t+0];
  float dy = coords[3*s+1] - coords[3*t+1];
  float dz = coords[3*s+2] - coords[3*t+2];
  dbuf[e] = sqrtf(dx*dx + dy*dy + dz*dz);
}

__global__ void k_starts(const int* __restrict__ ridx, int* __restrict__ starts, int A) {
  int a = blockIdx.x * blockDim.x + threadIdx.x;
  if (a >= A) return;
  if (a == 0 || ridx[a] != ridx[a-1]) starts[ridx[a]] = a;
}

// ---------------- counting sort of edges by dst ----------------------------
__global__ void k_hist(const int* __restrict__ edst, int* __restrict__ cnt, int E) {
  int e = blockIdx.x * blockDim.x + threadIdx.x;
  if (e < E) atomicAdd(&cnt[edst[e]], 1);
}

// two-level scan (was a single-block ~70us serial bottleneck)
__global__ __launch_bounds__(1024) void k_scanA(const int* __restrict__ cnt,
                                                int* __restrict__ cursor,
                                                int* __restrict__ bsum, int A) {
  __shared__ int buf[1024];
  int tid = threadIdx.x;
  int i = blockIdx.x * 1024 + tid;
  int v = (i < A) ? cnt[i] : 0;
  buf[tid] = v;
  __syncthreads();
  #pragma unroll
  for (int off = 1; off < 1024; off <<= 1) {
    int nv = (tid >= off) ? buf[tid - off] : 0;
    __syncthreads();
    buf[tid] += nv;
    __syncthreads();
  }
  if (i < A) cursor[i] = buf[tid] - v;   // exclusive within chunk
  if (tid == 1023) bsum[blockIdx.x] = buf[1023];
}

__global__ void k_scanB(int* __restrict__ bsum, int nb) {
  int lane = threadIdx.x;                 // one wave, nb <= 64
  int v = (lane < nb) ? bsum[lane] : 0;
  int s = v;
  #pragma unroll
  for (int off = 1; off < 64; off <<= 1) {
    int nv = __shfl_up(s, off);
    if (lane >= off) s += nv;
  }
  if (lane < nb) bsum[lane] = s - v;      // exclusive
}

__global__ void k_scanC(int* __restrict__ cursor, const int* __restrict__ bsum, int A) {
  int i = blockIdx.x * blockDim.x + threadIdx.x;
  if (i < A) cursor[i] += bsum[i >> 10];
}

__global__ void k_scatter(const int* __restrict__ edst, int* __restrict__ cursor,
                          int* __restrict__ eperm, int E) {
  int e = blockIdx.x * blockDim.x + threadIdx.x;
  if (e >= E) return;
  int p = atomicAdd(&cursor[edst[e]], 1);
  eperm[p] = e;
}

// ---------------- weight packing into per-lane-contiguous fragments --------
__global__ void k_pack(const float* __restrict__ We1, const float* __restrict__ We2,
                       const float* __restrict__ Wh1, const float* __restrict__ Wh2,
                       unsigned short* __restrict__ wp) {
  int t = blockIdx.x * blockDim.x + threadIdx.x;
  if (t >= WP_TOTAL) return;
  if (t < OFF_W2) {                      // rbf: We1 rows 256..271, K padded to 32
    int u = t - OFF_RBF; int layer = u / 4096, idx = u % 4096;
    int i = idx & 7, lane = (idx >> 3) & 63, ct = (idx >> 9) & 7;
    int k = ((lane >> 4) * 8) + i;
    int c = ct * 16 + (lane & 15);
    const float* src = We1 + (size_t)layer * 272 * H;
    wp[t] = f16u(k < 16 ? src[(size_t)(256 + k) * H + c] : 0.0f);
  } else if (t < OFF_PROJ) {             // We2 128x128
    int u = t - OFF_W2; int layer = u / 16384, idx = u % 16384;
    int i = idx & 7, lane = (idx >> 3) & 63, ct = (idx >> 9) & 7, kt = idx >> 12;
    int k = kt * 32 + (lane >> 4) * 8 + i, c = ct * 16 + (lane & 15);
    const float* src = We2 + (size_t)layer * 128 * H;
    wp[t] = f16u(src[(size_t)k * H + c]);
  } else if (t < OFF_H1) {               // proj: [We1_src | We1_dst] 128x256
    int u = t - OFF_PROJ; int layer = u / 32768, idx = u % 32768;
    int i = idx & 7, lane = (idx >> 3) & 63, ct = (idx >> 9) & 15, kt = idx >> 13;
    int k = kt * 32 + (lane >> 4) * 8 + i, c = ct * 16 + (lane & 15);
    const float* src = We1 + (size_t)layer * 272 * H;
    float v = (c < 128) ? src[(size_t)k * H + c] : src[(size_t)(128 + k) * H + (c - 128)];
    wp[t] = f16u(v);
  } else if (t < OFF_H2) {               // Wh1 256x128
    int u = t - OFF_H1; int layer = u / 32768, idx = u % 32768;
    int i = idx & 7, lane = (idx >> 3) & 63, ct = (idx >> 9) & 7, kt = idx >> 12;
    int k = kt * 32 + (lane >> 4) * 8 + i, c = ct * 16 + (lane & 15);
    const float* src = Wh1 + (size_t)layer * 256 * H;
    wp[t] = f16u(src[(size_t)k * H + c]);
  } else {                               // Wh2 128x128
    int u = t - OFF_H2; int layer = u / 16384, idx = u % 16384;
    int i = idx & 7, lane = (idx >> 3) & 63, ct = (idx >> 9) & 7, kt = idx >> 12;
    int k = kt * 32 + (lane >> 4) * 8 + i, c = ct * 16 + (lane & 15);
    const float* src = Wh2 + (size_t)layer * 128 * H;
    wp[t] = f16u(src[(size_t)k * H + c]);
  }
}

// ---------------- dense pre-projection: Ph = hb @ [We1_src|We1_dst] --------
__global__ __launch_bounds__(256) void k_proj(
    const unsigned short* __restrict__ hb, const unsigned short* __restrict__ Wp,
    unsigned short* __restrict__ Ph, int A) {
  const int tid = threadIdx.x, l = tid & 63, wv = tid >> 6;
  const int lr = l & 15, lk = (l >> 4) * 8;
  const int a0 = blockIdx.x * 64;
  f32x4 acc[4][4] = {};
  #pragma unroll
  for (int kt = 0; kt < 4; ++kt) {
    half8t a[4], b[4];
    #pragma unroll
    for (int rt = 0; rt < 4; ++rt) {
      int row = a0 + rt * 16 + lr; if (row >= A) row = A - 1;
      a[rt] = *(const half8t*)&hb[(size_t)row * H + kt * 32 + lk];
    }
    #pragma unroll
    for (int ci = 0; ci < 4; ++ci)
      b[ci] = *(const half8t*)&Wp[(((size_t)kt * 16 + wv * 4 + ci) * 64 + l) * 8];
    #pragma unroll
    for (int rt = 0; rt < 4; ++rt)
      #pragma unroll
      for (int ci = 0; ci < 4; ++ci)
        acc[rt][ci] = __builtin_amdgcn_mfma_f32_16x16x32_f16(a[rt], b[ci], acc[rt][ci], 0, 0, 0);
  }
  #pragma unroll
  for (int rt = 0; rt < 4; ++rt)
    #pragma unroll
    for (int ci = 0; ci < 4; ++ci) {
      int col = (wv * 4 + ci) * 16 + lr;
      #pragma unroll
      for (int rr = 0; rr < 4; ++rr) {
        int row = a0 + rt * 16 + (l >> 4) * 4 + rr;
        if (row < A) Ph[(size_t)row * 256 + col] = f16u(acc[rt][ci][rr]);
      }
    }
}

// ---------------- edge kernel (transposed compute: D = W^T @ X^T) ----------
#define PS 136    // Psum stride (fp16)
#define RS 40     // rbf stride (fp16)
#define M1S 136   // M1 stride (fp16)
#define M2SF 132  // M2 f32 stride

__global__ __launch_bounds__(256) void k_edge_mfma(
    const unsigned short* __restrict__ Ph, const float* __restrict__ dbuf,
    const int* __restrict__ esrc, const int* __restrict__ edst,
    const int* __restrict__ eperm,
    const unsigned short* __restrict__ Wr, const float* __restrict__ be1,
    const unsigned short* __restrict__ W2p, const float* __restrict__ be2,
    float* __restrict__ agg, int E) {
  __shared__ __align__(16) unsigned short SH[64*PS + 64*RS + 64*M1S];  // 39936 B
  __shared__ int dstv[64];
  unsigned short* Psum = SH;
  unsigned short* rbfs = SH + 64 * PS;
  unsigned short* M1s  = SH + 64 * (PS + RS);
  float* M2s = (float*)SH;   // 64*132*4 = 33792 B <= 39936

  const int tid = threadIdx.x;
  const int e0 = blockIdx.x * 64;
  // ---- stage: 4 threads per edge row; Psum[e][c] = Ph_src[c] + Ph_dst[c+128]
  {
    const int r = tid >> 2, qt = tid & 3;
    int e = e0 + r;
    int ec = (e < E) ? e : (E - 1);
    int es = eperm[ec];
    int s = esrc[es], t = edst[es];
    if (qt == 0) dstv[r] = (e < E) ? t : -1;
    const half8t* ps = (const half8t*)(Ph + (size_t)s * 256);        // src proj
    const half8t* pt = (const half8t*)(Ph + (size_t)t * 256 + 128);  // dst proj
    half8t* pr = (half8t*)&Psum[r * PS];
    #pragma unroll
    for (int i = 0; i < 4; ++i)
      pr[qt * 4 + i] = ps[qt * 4 + i] + pt[qt * 4 + i];   // v_pk_add_f16
    if (qt < 2) {
      float d = dbuf[es];
      #pragma unroll
      for (int i = 0; i < 8; ++i) {
        int j = qt * 8 + i;
        float dd = d - (float)j * (5.0f / 15.0f);
        rbfs[r * RS + j] = f16u(__expf(-10.24f * dd * dd));
      }
    } else if (qt == 2) {   // K-pad 16..31 must be zero
      #pragma unroll
      for (int i = 0; i < 16; ++i) rbfs[r * RS + 16 + i] = 0;
    }
  }
  __syncthreads();

  const int l = tid & 63, wv = tid >> 6;
  const int lr = l & 15, lk = (l >> 4) * 8, g4 = (l >> 4) * 4;
  const int ct0 = wv * 2;

  // ---- mm1T: acc[cj][et] = Psum^T (direct b64 read) + We1rbf^T @ rbf^T ----
  f32x4 acc[2][4];
  #pragma unroll
  for (int cj = 0; cj < 2; ++cj) {
    int cbase = (ct0 + cj) * 16 + g4;
    #pragma unroll
    for (int et = 0; et < 4; ++et) {
      half4t p4 = *(const half4t*)&Psum[(et * 16 + lr) * PS + cbase];
      acc[cj][et][0] = (float)p4[0];
      acc[cj][et][1] = (float)p4[1];
      acc[cj][et][2] = (float)p4[2];
      acc[cj][et][3] = (float)p4[3];
    }
  }
  {
    half8t ar[2];
    #pragma unroll
    for (int cj = 0; cj < 2; ++cj)
      ar[cj] = *(const half8t*)&Wr[(((size_t)(ct0 + cj)) * 64 + l) * 8];
    #pragma unroll
    for (int et = 0; et < 4; ++et) {
      half8t br = *(const half8t*)&rbfs[(et * 16 + lr) * RS + lk];
      #pragma unroll
      for (int cj = 0; cj < 2; ++cj)
        acc[cj][et] = __builtin_amdgcn_mfma_f32_16x16x32_f16(ar[cj], br, acc[cj][et], 0, 0, 0);
    }
  }
  // silu(acc + be1) -> M1[e][c] as packed b64
  #pragma unroll
  for (int cj = 0; cj < 2; ++cj) {
    f32x4 b1v = *(const f32x4*)&be1[(ct0 + cj) * 16 + g4];
    #pragma unroll
    for (int et = 0; et < 4; ++et) {
      half4t m4;
      #pragma unroll
      for (int rr = 0; rr < 4; ++rr)
        m4[rr] = (_Float16)silu_f(acc[cj][et][rr] + b1v[rr]);
      *(half4t*)&M1s[(et * 16 + lr) * M1S + (ct0 + cj) * 16 + g4] = m4;
    }
  }
  __syncthreads();

  // ---- mm2T: acc2 = We2^T @ M1^T ----
  f32x4 acc2[2][4] = {};
  #pragma unroll
  for (int kt = 0; kt < 4; ++kt) {
    half8t a2[2], b2[4];
    #pragma unroll
    for (int cj = 0; cj < 2; ++cj)
      a2[cj] = *(const half8t*)&W2p[(((size_t)kt * 8 + ct0 + cj) * 64 + l) * 8];
    #pragma unroll
    for (int et = 0; et < 4; ++et)
      b2[et] = *(const half8t*)&M1s[(et * 16 + lr) * M1S + kt * 32 + lk];
    #pragma unroll
    for (int cj = 0; cj < 2; ++cj)
      #pragma unroll
      for (int et = 0; et < 4; ++et)
        acc2[cj][et] = __builtin_amdgcn_mfma_f32_16x16x32_f16(a2[cj], b2[et], acc2[cj][et], 0, 0, 0);
  }
  __syncthreads();   // all Psum/M1 reads done -> safe to alias-write M2
  #pragma unroll
  for (int cj = 0; cj < 2; ++cj) {
    f32x4 b2v = *(const f32x4*)&be2[(ct0 + cj) * 16 + g4];
    #pragma unroll
    for (int et = 0; et < 4; ++et) {
      f32x4 w;
      #pragma unroll
      for (int rr = 0; rr < 4; ++rr)
        w[rr] = silu_f(acc2[cj][et][rr] + b2v[rr]);
      *(f32x4*)&M2s[(et * 16 + lr) * M2SF + (ct0 + cj) * 16 + g4] = w;
    }
  }
  __syncthreads();

  // ---- segmented reduce over dst runs: thread = (colpair, row-quarter) ----
  {
    int cp = tid & 63, qr = tid >> 6;
    int rbeg = qr * 16, rend = rbeg + 16;
    float a0 = 0.f, a1 = 0.f;
    int prev = -1;
    for (int r = rbeg; r < rend; ++r) {
      int dv = dstv[r];
      float2 v = *(const float2*)&M2s[r * M2SF + cp * 2];
      if (dv != prev) {
        if (prev >= 0) {
          atomicAdd(&agg[(size_t)prev * H + cp * 2], a0);
          atomicAdd(&agg[(size_t)prev * H + cp * 2 + 1], a1);
        }
        a0 = a1 = 0.f;
        prev = dv;
      }
      if (dv >= 0) { a0 += v.x; a1 += v.y; }
    }
    if (prev >= 0) {
      atomicAdd(&agg[(size_t)prev * H + cp * 2], a0);
      atomicAdd(&agg[(size_t)prev * H + cp * 2 + 1], a1);
    }
  }
}

// ---------------- node MLP: fp16 MFMA, 32 atoms/block ----------------------
#define NXS 264   // X stride fp16 (528B)

__global__ __launch_bounds__(256) void k_node_mfma(
    float* __restrict__ h, unsigned short* __restrict__ hb,
    const float* __restrict__ agg,
    const unsigned short* __restrict__ W1p, const float* __restrict__ bh1,
    const unsigned short* __restrict__ W2p, const float* __restrict__ bh2, int A) {
  __shared__ __align__(16) unsigned short Xs[32 * NXS];   // 16896 B
  __shared__ __align__(16) unsigned short Us[32 * M1S];   //  8704 B
  const int tid = threadIdx.x;
  const int a0 = blockIdx.x * 32;
  {
    const int r = tid >> 3, oct = tid & 7;   // 8 threads per atom row
    int a = a0 + r; if (a >= A) a = A - 1;
    const u16x8* hr = (const u16x8*)(hb + (size_t)a * H);
    u16x8* xr = (u16x8*)&Xs[r * NXS];
    xr[oct * 2]     = hr[oct * 2];
    xr[oct * 2 + 1] = hr[oct * 2 + 1];
    const float4* ar = (const float4*)(agg + (size_t)a * H);
    u16x8 tmp[2];
    unsigned short* tp = (unsigned short*)tmp;
    #pragma unroll
    for (int i = 0; i < 4; ++i) {
      float4 av = ar[oct * 4 + i];
      tp[i*4+0] = f16u(av.x); tp[i*4+1] = f16u(av.y);
      tp[i*4+2] = f16u(av.z); tp[i*4+3] = f16u(av.w);
    }
    xr[16 + oct * 2]     = tmp[0];
    xr[16 + oct * 2 + 1] = tmp[1];
  }
  __syncthreads();

  const int l = tid & 63, wv = tid >> 6;
  const int lr = l & 15, lk = (l >> 4) * 8;
  const int ct0 = wv * 2;
  const int c0 = ct0 * 16 + lr, c1 = c0 + 16;
  const float b1a = bh1[c0], b1b = bh1[c1];
  const float b2a = bh2[c0], b2b = bh2[c1];

  f32x4 acc[2][2] = {};
  #pragma unroll
  for (int kt = 0; kt < 8; ++kt) {
    half8t a[2], b[2];
    #pragma unroll
    for (int rt = 0; rt < 2; ++rt)
      a[rt] = *(const half8t*)&Xs[(rt * 16 + lr) * NXS + kt * 32 + lk];
    #pragma unroll
    for (int j = 0; j < 2; ++j)
      b[j] = *(const half8t*)&W1p[(((size_t)kt * 8 + ct0 + j) * 64 + l) * 8];
    #pragma unroll
    for (int rt = 0; rt < 2; ++rt)
      #pragma unroll
      for (int j = 0; j < 2; ++j)
        acc[rt][j] = __builtin_amdgcn_mfma_f32_16x16x32_f16(a[rt], b[j], acc[rt][j], 0, 0, 0);
  }
  #pragma unroll
  for (int rt = 0; rt < 2; ++rt)
    #pragma unroll
    for (int j = 0; j < 2; ++j) {
      float bb = j ? b1b : b1a;
      int col = (ct0 + j) * 16 + lr;
      #pragma unroll
      for (int rr = 0; rr < 4; ++rr) {
        int row = rt * 16 + (l >> 4) * 4 + rr;
        Us[row * M1S + col] = f16u(silu_f(acc[rt][j][rr] + bb));
      }
    }
  __syncthreads();

  f32x4 acc2[2][2] = {};
  #pragma unroll
  for (int kt = 0; kt < 4; ++kt) {
    half8t a[2], b[2];
    #pragma unroll
    for (int rt = 0; rt < 2; ++rt)
      a[rt] = *(const half8t*)&Us[(rt * 16 + lr) * M1S + kt * 32 + lk];
    #pragma unroll
    for (int j = 0; j < 2; ++j)
      b[j] = *(const half8t*)&W2p[(((size_t)kt * 8 + ct0 + j) * 64 + l) * 8];
    #pragma unroll
    for (int rt = 0; rt < 2; ++rt)
      #pragma unroll
      for (int j = 0; j < 2; ++j)
        acc2[rt][j] = __builtin_amdgcn_mfma_f32_16x16x32_f16(a[rt], b[j], acc2[rt][j], 0, 0, 0);
  }
  #pragma unroll
  for (int rt = 0; rt < 2; ++rt)
    #pragma unroll
    for (int j = 0; j < 2; ++j) {
      float bb = j ? b2b : b2a;
      int col = (ct0 + j) * 16 + lr;
      #pragma unroll
      for (int rr = 0; rr < 4; ++rr) {
        int row = rt * 16 + (l >> 4) * 4 + rr;
        int a = a0 + row;
        if (a < A) {
          size_t off = (size_t)a * H + col;
          float nh = h[off] + acc2[rt][j][rr] + bb;
          h[off] = nh;
          hb[off] = f16u(nh);
        }
      }
    }
}

// ---------------- tail kernels (f32, known-correct) ------------------------
// merged k+v projection: shares one X stage
__global__ __launch_bounds__(256) void k_linear2(
    const float* __restrict__ in,
    const float* __restrict__ W1, const float* __restrict__ b1, float* __restrict__ out1,
    const float* __restrict__ W2, const float* __restrict__ b2, float* __restrict__ out2,
    int nrows) {
  __shared__ float X[32][132];
  const int tid = threadIdx.x, lane = tid & 63, wv = tid >> 6;
  const int r0 = blockIdx.x * 32;
  #pragma unroll
  for (int i = 0; i < 8; ++i) {
    int r = wv * 8 + i;
    int a = r0 + r; if (a >= nrows) a = nrows - 1;
    X[r][lane]      = in[(size_t)a*H + lane];
    X[r][64 + lane] = in[(size_t)a*H + 64 + lane];
  }
  __syncthreads();
  const int rowg = tid >> 5, c0 = (tid & 31) * 4;
  {
    float acc[4][4] = {};
    mm4x4<128>(&X[rowg*4][0], 132, W1, c0, acc);
    #pragma unroll
    for (int rr = 0; rr < 4; ++rr) {
      int a = r0 + rowg*4 + rr;
      if (a < nrows)
        #pragma unroll
        for (int cc = 0; cc < 4; ++cc)
          out1[(size_t)a*H + c0 + cc] = acc[rr][cc] + b1[c0+cc];
    }
  }
  {
    float acc[4][4] = {};
    mm4x4<128>(&X[rowg*4][0], 132, W2, c0, acc);
    #pragma unroll
    for (int rr = 0; rr < 4; ++rr) {
      int a = r0 + rowg*4 + rr;
      if (a < nrows)
        #pragma unroll
        for (int cc = 0; cc < 4; ++cc)
          out2[(size_t)a*H + c0 + cc] = acc[rr][cc] + b2[c0+cc];
    }
  }
}

__global__ void k_q(const float* __restrict__ residue_embed,
                    const int* __restrict__ rtype,
                    const float* __restrict__ Wq, const float* __restrict__ bq,
                    float* __restrict__ q, int N) {
  int i = blockIdx.x * blockDim.x + threadIdx.x;
  if (i >= N * H) return;
  int r = i >> 7, j = i & 127;
  const float* emb = residue_embed + (size_t)rtype[r] * H;
  float s = bq[j];
  #pragma unroll 4
  for (int k = 0; k < H; ++k) s += emb[k] * Wq[(size_t)k*H + j];
  q[i] = s;
}

__global__ __launch_bounds__(256) void k_pool(
    const float* __restrict__ q, const float* __restrict__ kbuf,
    const float* __restrict__ vbuf, const int* __restrict__ starts,
    const int* __restrict__ apr, float* __restrict__ pooled, int N) {
  int r = blockIdx.x * 4 + (threadIdx.x >> 6);
  if (r >= N) return;
  int lane = threadIdx.x & 63;
  int s0 = starts[r], cnt = apr[r];
  float q0 = q[(size_t)r*H + lane], q1 = q[(size_t)r*H + 64 + lane];
  float myscore = -1e30f;
  for (int i = 0; i < cnt; ++i) {
    size_t a = (size_t)(s0 + i) * H;
    float p = q0 * kbuf[a + lane] + q1 * kbuf[a + 64 + lane];
    #pragma unroll
    for (int off = 32; off; off >>= 1) p += __shfl_xor(p, off);
    if (lane == i) myscore = p * 0.08838834764831845f;
  }
  float val = (lane < cnt) ? myscore : -1e30f;
  float mx = val;
  #pragma unroll
  for (int off = 32; off; off >>= 1) mx = fmaxf(mx, __shfl_xor(mx, off));
  float ex = (lane < cnt) ? __expf(val - mx) : 0.0f;
  float sum = ex;
  #pragma unroll
  for (int off = 32; off; off >>= 1) sum += __shfl_xor(sum, off);
  float w = ex * __builtin_amdgcn_rcpf(sum);
  float p0 = 0.f, p1 = 0.f;
  for (int i = 0; i < cnt; ++i) {
    float wi = __shfl(w, i);
    size_t a = (size_t)(s0 + i) * H;
    p0 += wi * vbuf[a + lane];
    p1 += wi * vbuf[a + 64 + lane];
  }
  pooled[(size_t)r*H + lane] = p0;
  pooled[(size_t)r*H + 64 + lane] = p1;
}

__global__ void k_head(const float* __restrict__ pooled,
                       const float* __restrict__ Wmu, const float* __restrict__ bmu,
                       const float* __restrict__ Wlv, const float* __restrict__ blv,
                       float* __restrict__ out, int N) {
  int i = blockIdx.x * blockDim.x + threadIdx.x;
  if (i >= N * LATD) return;
  int r = i >> 5, j = i & 31;
  const float* p = pooled + (size_t)r * H;
  float smu = 0.f, slv = 0.f;
  #pragma unroll 4
  for (int k = 0; k < H; ++k) {
    float pv = p[k];
    smu += pv * Wmu[(size_t)k*LATD + j];
    slv += pv * Wlv[(size_t)k*LATD + j];
  }
  smu += bmu[j];
  slv += blv[j];
  slv = fminf(fmaxf(slv, -10.0f), 2.0f);
  out[i] = smu;
  out[(size_t)N*LATD + i] = slv;
}

extern "C" void kernel_launch(void* const* d_in, const int* in_sizes, int n_in,
                              void* d_out, int out_size, void* d_ws, size_t ws_size,
                              hipStream_t stream) {
  const float* coords        = (const float*)d_in[0];
  const int*   atype         = (const int*)d_in[1];
  const int*   ridx          = (const int*)d_in[2];
  const int*   rtype         = (const int*)d_in[3];
  const int*   apr           = (const int*)d_in[4];
  const int*   esrc          = (const int*)d_in[5];
  const int*   edst          = (const int*)d_in[6];
  const float* atom_embed    = (const float*)d_in[7];
  const float* residue_embed = (const float*)d_in[8];
  const float* We1 = (const float*)d_in[9];
  const float* be1 = (const float*)d_in[10];
  const float* We2 = (const float*)d_in[11];
  const float* be2 = (const float*)d_in[12];
  const float* Wh1 = (const float*)d_in[13];
  const float* bh1 = (const float*)d_in[14];
  const float* Wh2 = (const float*)d_in[15];
  const float* bh2 = (const float*)d_in[16];
  const float* Wq  = (const float*)d_in[17];
  const float* bq  = (const float*)d_in[18];
  const float* Wk  = (const float*)d_in[19];
  const float* bk  = (const float*)d_in[20];
  const float* Wv  = (const float*)d_in[21];
  const float* bv  = (const float*)d_in[22];
  const float* Wmu = (const float*)d_in[23];
  const float* bmu = (const float*)d_in[24];
  const float* Wlv = (const float*)d_in[25];
  const float* blv = (const float*)d_in[26];

  const int A = in_sizes[1];
  const int N = in_sizes[3];
  const int E = in_sizes[5];

  float* ws     = (float*)d_ws;
  float* h      = ws;                              // A*H f32
  float* agg    = h + (size_t)A * H;               // A*H f32
  float* vbuf   = agg + (size_t)A * H;             // A*H f32 (aliases Ph)
  float* dbuf   = vbuf + (size_t)A * H;            // E f32
  float* qbuf   = dbuf + (size_t)E;                // N*H
  float* pooled = qbuf + (size_t)N * H;            // N*H
  int*   starts = (int*)(pooled + (size_t)N * H);  // N
  unsigned short* hbuf = (unsigned short*)(starts + N);  // A*H fp16
  int*   eperm  = (int*)(hbuf + (size_t)A * H);    // E
  int*   cnt    = eperm + (size_t)E;               // A
  int*   cursor = cnt + A;                         // A
  int*   bsum   = cursor + A;                      // 64
  unsigned short* wp = (unsigned short*)(bsum + 64);     // WP_TOTAL fp16
  unsigned short* Ph = (unsigned short*)vbuf;      // A*256 fp16 == A*H f32 bytes

  k_init_h<<<(A * H + 255) / 256, 256, 0, stream>>>(atom_embed, residue_embed,
                                                    atype, ridx, rtype, h, hbuf, A);
  k_dist<<<(E + 255) / 256, 256, 0, stream>>>(coords, esrc, edst, dbuf, E);
  k_starts<<<(A + 255) / 256, 256, 0, stream>>>(ridx, starts, A);
  k_pack<<<(WP_TOTAL + 255) / 256, 256, 0, stream>>>(We1, We2, Wh1, Wh2, wp);

  // counting sort of edges by dst (two-level scan)
  const int nb = (A + 1023) / 1024;   // 44 for A=45056
  hipMemsetAsync(cnt, 0, (size_t)A * sizeof(int), stream);
  k_hist<<<(E + 255) / 256, 256, 0, stream>>>(edst, cnt, E);
  k_scanA<<<nb, 1024, 0, stream>>>(cnt, cursor, bsum, A);
  k_scanB<<<1, 64, 0, stream>>>(bsum, nb);
  k_scanC<<<(A + 255) / 256, 256, 0, stream>>>(cursor, bsum, A);
  k_scatter<<<(E + 255) / 256, 256, 0, stream>>>(edst, cursor, eperm, E);

  for (int l = 0; l < 3; ++l) {
    hipMemsetAsync(agg, 0, (size_t)A * H * sizeof(float), stream);
    k_proj<<<(A + 63) / 64, 256, 0, stream>>>(
        hbuf, wp + OFF_PROJ + (size_t)l * 32768, Ph, A);
    k_edge_mfma<<<(E + 63) / 64, 256, 0, stream>>>(
        Ph, dbuf, esrc, edst, eperm,
        wp + OFF_RBF + (size_t)l * 4096,  be1 + (size_t)l * H,
        wp + OFF_W2  + (size_t)l * 16384, be2 + (size_t)l * H, agg, E);
    k_node_mfma<<<(A + 31) / 32, 256, 0, stream>>>(
        h, hbuf, agg,
        wp + OFF_H1 + (size_t)l * 32768, bh1 + (size_t)l * H,
        wp + OFF_H2 + (size_t)l * 16384, bh2 + (size_t)l * H, A);
  }

  k_q<<<(N * H + 255) / 256, 256, 0, stream>>>(residue_embed, rtype, Wq, bq, qbuf, N);
  float* kbuf = agg;  // reuse
  k_linear2<<<(A + 31) / 32, 256, 0, stream>>>(h, Wk, bk, kbuf, Wv, bv, vbuf, A);
  k_pool<<<(N + 3) / 4, 256, 0, stream>>>(qbuf, kbuf, vbuf, starts, apr, pooled, N);
  k_head<<<(N * LATD + 255) / 256, 256, 0, stream>>>(pooled, Wmu, bmu, Wlv, blv,
                                                     (float*)d_out, N);
}